// Round 6
// baseline (528.354 us; speedup 1.0000x reference)
//
#include <hip/hip_runtime.h>
#include <hip/hip_bf16.h>

#define B_ 4
#define T_ 2048
#define E_ 1024
#define H_ 16
#define HS_ 64
#define DFF_ 4096
#define M_ (B_ * T_)   // 8192 tokens
#define LDQ_ (3 * E_)  // qkv fused row stride

typedef __bf16 bf16_t;
typedef __bf16 bf16x4 __attribute__((ext_vector_type(4)));
typedef __bf16 bf16x8 __attribute__((ext_vector_type(8)));
typedef float f32x4 __attribute__((ext_vector_type(4)));

#define AS1 __attribute__((address_space(1)))
#define AS3 __attribute__((address_space(3)))

__device__ __forceinline__ void gload_lds16(const void* g, void* l) {
  __builtin_amdgcn_global_load_lds((AS1 void*)(g), (AS3 void*)(l), 16, 0, 0);
}

// ---------------------------------------------------------------------------
// Weight convert+transpose: W fp32 [Krows][Ncols] -> Wt bf16 [Ncols][Krows]
// ---------------------------------------------------------------------------
__global__ __launch_bounds__(256) void wtrans_kernel(
    const float* __restrict__ W, bf16_t* __restrict__ Wt, int Krows, int Ncols) {
  __shared__ float tile[32][33];
  int tx = threadIdx.x, ty = threadIdx.y;  // (32,8)
  int n0 = blockIdx.x * 32, k0 = blockIdx.y * 32;
#pragma unroll
  for (int i = 0; i < 32; i += 8)
    tile[ty + i][tx] = W[(long)(k0 + ty + i) * Ncols + n0 + tx];
  __syncthreads();
#pragma unroll
  for (int i = 0; i < 32; i += 8)
    Wt[(long)(n0 + ty + i) * Krows + k0 + tx] = (bf16_t)tile[tx][ty + i];
}

// bias concat: [bq | bk | bv] -> 3072 floats
__global__ __launch_bounds__(256) void bcat_kernel(const float* a, const float* b,
                                                   const float* c, float* o) {
  int i = blockIdx.x * 256 + threadIdx.x;
  o[i] = i < 1024 ? a[i] : (i < 2048 ? b[i - 1024] : c[i - 2048]);
}

// ---------------------------------------------------------------------------
// LayerNorm: fp32 [M][1024] -> bf16 [M][1024]
// ---------------------------------------------------------------------------
__global__ __launch_bounds__(256) void layernorm_kernel(
    const float* __restrict__ in, const float* __restrict__ g,
    const float* __restrict__ b, bf16_t* __restrict__ out) {
  int row = blockIdx.x;
  int tid = threadIdx.x;
  const float4* inr = (const float4*)(in + (long)row * E_);
  float4 v = inr[tid];
  float s = v.x + v.y + v.z + v.w;
  float ss = v.x * v.x + v.y * v.y + v.z * v.z + v.w * v.w;
#pragma unroll
  for (int o = 32; o; o >>= 1) {
    s += __shfl_xor(s, o);
    ss += __shfl_xor(ss, o);
  }
  __shared__ float red[8];
  int wv = tid >> 6;
  if ((tid & 63) == 0) {
    red[wv] = s;
    red[4 + wv] = ss;
  }
  __syncthreads();
  s = red[0] + red[1] + red[2] + red[3];
  ss = red[4] + red[5] + red[6] + red[7];
  float mu = s * (1.f / E_);
  float var = ss * (1.f / E_) - mu * mu;
  float rs = rsqrtf(var + 1e-5f);
  int ci = tid * 4;
  float4 gv = *(const float4*)(g + ci);
  float4 bv = *(const float4*)(b + ci);
  long o0 = (long)row * E_ + ci;
  out[o0 + 0] = (bf16_t)((v.x - mu) * rs * gv.x + bv.x);
  out[o0 + 1] = (bf16_t)((v.y - mu) * rs * gv.y + bv.y);
  out[o0 + 2] = (bf16_t)((v.z - mu) * rs * gv.z + bv.z);
  out[o0 + 3] = (bf16_t)((v.w - mu) * rs * gv.w + bv.w);
}

// ---------------------------------------------------------------------------
// GEMM (256x256 path, FF1): BK=32, 8 waves (2Mx4N, per-wave 128x64),
// 4-deep ring of K-tiles in statically-named LDS slots (alias-analysis-proof:
// r2 lesson), counted vmcnt, loop unrolled x4. K % 128 == 0.
// RELU 0: bf16 + bias; RELU 1: bf16 relu(+bias).
// ---------------------------------------------------------------------------
template <int RELU>
__global__ __launch_bounds__(512, 2) void gemm256_kernel(
    const bf16_t* __restrict__ A, const bf16_t* __restrict__ Bt,
    const float* __restrict__ bias, bf16_t* __restrict__ out, int N, int K) {
  __shared__ bf16_t As0[256 * 32], As1[256 * 32], As2[256 * 32], As3[256 * 32];
  __shared__ bf16_t Bs0[256 * 32], Bs1[256 * 32], Bs2[256 * 32], Bs3[256 * 32];
  const int tid = threadIdx.x;
  const int wave = tid >> 6;  // 0..7
  const int lane = tid & 63;
  const int wr = wave >> 2;   // 0..1 : row half (128 rows)
  const int wc = wave & 3;    // 0..3 : col quarter (64 cols)
  const int quad = lane >> 4, l16 = lane & 15;

  const int gx = gridDim.x;
  const int id = blockIdx.y * gx + blockIdx.x;
  const int xcd = id & 7;
  const int k_ = id >> 3;
  const int bxr = k_ % gx;
  const int byr = (k_ / gx) * 8 + xcd;
  const long rowBase = (long)byr * 256;
  const long colBase = (long)bxr * 256;

  f32x4 acc[8][4] = {};  // [mh*4+fr][fc]

  const int ntiles = K >> 5;  // multiple of 4

  auto stageA = [&](bf16_t* dst, int t) {
    const int k0 = t << 5;
#pragma unroll
    for (int p = 0; p < 2; ++p) {
      int idx = p * 512 + tid;  // chunk id 0..1023
      int row = idx >> 2;       // 0..255
      int col = (idx & 3) * 8;  // 0,8,16,24
      gload_lds16(&A[(rowBase + row) * K + k0 + col],
                  dst + (p * 512 + wave * 64) * 8);
    }
  };
  auto stageB = [&](bf16_t* dst, int t) {
    const int k0 = t << 5;
#pragma unroll
    for (int p = 0; p < 2; ++p) {
      int idx = p * 512 + tid;
      int row = idx >> 2;
      int col = (idx & 3) * 8;
      gload_lds16(&Bt[(colBase + row) * K + k0 + col],
                  dst + (p * 512 + wave * 64) * 8);
    }
  };

  auto tileStep = [&](int t, const bf16_t* as, const bf16_t* bs, bf16_t* nA,
                      bf16_t* nB) {
    const bool pre = (t + 3 < ntiles);
    bf16x8 bfrag[4];
#pragma unroll
    for (int fc = 0; fc < 4; ++fc)
      bfrag[fc] = *(const bf16x8*)&bs[(wc * 64 + fc * 16 + l16) * 32 + quad * 8];

    // ---- phase 0: row-half mh=0 ----
    {
      bf16x8 afrag[4];
#pragma unroll
      for (int fr = 0; fr < 4; ++fr)
        afrag[fr] =
            *(const bf16x8*)&as[(wr * 128 + fr * 16 + l16) * 32 + quad * 8];
      if (pre) stageA(nA, t + 3);
      __builtin_amdgcn_s_setprio(1);
#pragma unroll
      for (int fr = 0; fr < 4; ++fr)
#pragma unroll
        for (int fc = 0; fc < 4; ++fc)
          acc[fr][fc] = __builtin_amdgcn_mfma_f32_16x16x32_bf16(
              afrag[fr], bfrag[fc], acc[fr][fc], 0, 0, 0);
      __builtin_amdgcn_s_setprio(0);
      __builtin_amdgcn_s_barrier();
    }
    // ---- phase 1: row-half mh=1 ----
    {
      bf16x8 afrag[4];
#pragma unroll
      for (int fr = 0; fr < 4; ++fr)
        afrag[fr] = *(const bf16x8*)&as[(wr * 128 + 64 + fr * 16 + l16) * 32 +
                                        quad * 8];
      if (pre) stageB(nB, t + 3);
      __builtin_amdgcn_s_setprio(1);
#pragma unroll
      for (int fr = 0; fr < 4; ++fr)
#pragma unroll
        for (int fc = 0; fc < 4; ++fc)
          acc[4 + fr][fc] = __builtin_amdgcn_mfma_f32_16x16x32_bf16(
              afrag[fr], bfrag[fc], acc[4 + fr][fc], 0, 0, 0);
      __builtin_amdgcn_s_setprio(0);
      if (t + 3 < ntiles)
        asm volatile("s_waitcnt vmcnt(8)" ::: "memory");
      else if (t + 2 < ntiles)
        asm volatile("s_waitcnt vmcnt(4)" ::: "memory");
      else if (t + 1 < ntiles)
        asm volatile("s_waitcnt vmcnt(0)" ::: "memory");
      if (t + 1 < ntiles) __builtin_amdgcn_s_barrier();
    }
  };

  stageA(As0, 0); stageB(Bs0, 0);
  stageA(As1, 1); stageB(Bs1, 1);
  stageA(As2, 2); stageB(Bs2, 2);
  asm volatile("s_waitcnt vmcnt(8)" ::: "memory");
  __builtin_amdgcn_s_barrier();

  for (int t = 0; t < ntiles; t += 4) {
    tileStep(t + 0, As0, Bs0, As3, Bs3);
    tileStep(t + 1, As1, Bs1, As0, Bs0);
    tileStep(t + 2, As2, Bs2, As1, Bs1);
    tileStep(t + 3, As3, Bs3, As2, Bs2);
  }

#pragma unroll
  for (int mh = 0; mh < 2; ++mh)
#pragma unroll
    for (int fr = 0; fr < 4; ++fr)
#pragma unroll
      for (int fc = 0; fc < 4; ++fc) {
        int colg = (int)colBase + wc * 64 + fc * 16 + l16;
        float bv = bias[colg];
#pragma unroll
        for (int r = 0; r < 4; ++r) {
          long rowg = rowBase + wr * 128 + mh * 64 + fr * 16 + quad * 4 + r;
          float v = acc[mh * 4 + fr][fc][r] + bv;
          if (RELU) v = fmaxf(v, 0.f);
          out[rowg * N + colg] = (bf16_t)v;
        }
      }
}

// ---------------------------------------------------------------------------
// GEMM (256x128 path, QKV/proj/FF2): 8 waves (4r x 2c, per-wave 64x64),
// named-slot 4-deep ring + counted vmcnt. LDS 96KB, 1 block/CU.
// 3 loads per K-tile -> steady-state vmcnt(6). K % 128 == 0.
// MODE 0: bf16 store of C+bias; MODE 1: fp32 store of C+bias+resid.
// ---------------------------------------------------------------------------
template <int MODE>
__global__ __launch_bounds__(512, 1) void gemm256x128_kernel(
    const bf16_t* __restrict__ A, const bf16_t* __restrict__ Bt,
    const float* __restrict__ bias, const float* __restrict__ resid,
    void* __restrict__ out, int N, int K) {
  __shared__ bf16_t As0[256 * 32], As1[256 * 32], As2[256 * 32], As3[256 * 32];
  __shared__ bf16_t Bs0[128 * 32], Bs1[128 * 32], Bs2[128 * 32], Bs3[128 * 32];
  const int tid = threadIdx.x;
  const int wave = tid >> 6;  // 0..7
  const int lane = tid & 63;
  const int wr = wave >> 1;   // 0..3 : 64-row band
  const int wc = wave & 1;    // 0..1 : 64-col half
  const int quad = lane >> 4, l16 = lane & 15;

  const int gx = gridDim.x;
  const int id = blockIdx.y * gx + blockIdx.x;
  const int xcd = id & 7;
  const int k_ = id >> 3;
  const int bxr = k_ % gx;
  const int byr = (k_ / gx) * 8 + xcd;
  const long rowBase = (long)byr * 256;
  const long colBase = (long)bxr * 128;

  f32x4 acc[4][4] = {};  // [fr][fc]

  const int ntiles = K >> 5;  // multiple of 4

  auto stageA = [&](bf16_t* dst, int t) {
    const int k0 = t << 5;
#pragma unroll
    for (int p = 0; p < 2; ++p) {
      int idx = p * 512 + tid;
      int row = idx >> 2;       // 0..255
      int col = (idx & 3) * 8;  // 0,8,16,24
      gload_lds16(&A[(rowBase + row) * K + k0 + col],
                  dst + (p * 512 + wave * 64) * 8);
    }
  };
  auto stageB = [&](bf16_t* dst, int t) {
    const int k0 = t << 5;
    int row = tid >> 2;       // 0..127
    int col = (tid & 3) * 8;  // 0,8,16,24
    gload_lds16(&Bt[(colBase + row) * K + k0 + col], dst + (wave * 64) * 8);
  };

  auto tileStep = [&](int t, const bf16_t* as, const bf16_t* bs, bf16_t* nA,
                      bf16_t* nB) {
    const bool pre = (t + 3 < ntiles);
    bf16x8 bfrag[4];
#pragma unroll
    for (int fc = 0; fc < 4; ++fc)
      bfrag[fc] = *(const bf16x8*)&bs[(wc * 64 + fc * 16 + l16) * 32 + quad * 8];

    // ---- phase 0: rows fr=0,1 ----
    {
      bf16x8 afrag[2];
#pragma unroll
      for (int fr = 0; fr < 2; ++fr)
        afrag[fr] =
            *(const bf16x8*)&as[(wr * 64 + fr * 16 + l16) * 32 + quad * 8];
      if (pre) stageA(nA, t + 3);
      __builtin_amdgcn_s_setprio(1);
#pragma unroll
      for (int fr = 0; fr < 2; ++fr)
#pragma unroll
        for (int fc = 0; fc < 4; ++fc)
          acc[fr][fc] = __builtin_amdgcn_mfma_f32_16x16x32_bf16(
              afrag[fr], bfrag[fc], acc[fr][fc], 0, 0, 0);
      __builtin_amdgcn_s_setprio(0);
      __builtin_amdgcn_s_barrier();
    }
    // ---- phase 1: rows fr=2,3 ----
    {
      bf16x8 afrag[2];
#pragma unroll
      for (int fr = 2; fr < 4; ++fr)
        afrag[fr - 2] =
            *(const bf16x8*)&as[(wr * 64 + fr * 16 + l16) * 32 + quad * 8];
      if (pre) stageB(nB, t + 3);
      __builtin_amdgcn_s_setprio(1);
#pragma unroll
      for (int fr = 2; fr < 4; ++fr)
#pragma unroll
        for (int fc = 0; fc < 4; ++fc)
          acc[fr][fc] = __builtin_amdgcn_mfma_f32_16x16x32_bf16(
              afrag[fr - 2], bfrag[fc], acc[fr][fc], 0, 0, 0);
      __builtin_amdgcn_s_setprio(0);
      if (t + 3 < ntiles)
        asm volatile("s_waitcnt vmcnt(6)" ::: "memory");
      else if (t + 2 < ntiles)
        asm volatile("s_waitcnt vmcnt(3)" ::: "memory");
      else if (t + 1 < ntiles)
        asm volatile("s_waitcnt vmcnt(0)" ::: "memory");
      if (t + 1 < ntiles) __builtin_amdgcn_s_barrier();
    }
  };

  stageA(As0, 0); stageB(Bs0, 0);
  stageA(As1, 1); stageB(Bs1, 1);
  stageA(As2, 2); stageB(Bs2, 2);
  asm volatile("s_waitcnt vmcnt(6)" ::: "memory");
  __builtin_amdgcn_s_barrier();

  for (int t = 0; t < ntiles; t += 4) {
    tileStep(t + 0, As0, Bs0, As3, Bs3);
    tileStep(t + 1, As1, Bs1, As0, Bs0);
    tileStep(t + 2, As2, Bs2, As1, Bs1);
    tileStep(t + 3, As3, Bs3, As2, Bs2);
  }

#pragma unroll
  for (int fr = 0; fr < 4; ++fr)
#pragma unroll
    for (int fc = 0; fc < 4; ++fc) {
      int colg = (int)colBase + wc * 64 + fc * 16 + l16;
      float bv = bias[colg];
#pragma unroll
      for (int r = 0; r < 4; ++r) {
        long rowg = rowBase + wr * 64 + fr * 16 + quad * 4 + r;
        float v = acc[fr][fc][r] + bv;
        long idx = rowg * N + colg;
        if (MODE == 0) {
          ((bf16_t*)out)[idx] = (bf16_t)v;
        } else {
          ((float*)out)[idx] = v + resid[idx];
        }
      }
    }
}

// ---------------------------------------------------------------------------
// V transpose: qkv bf16 [B*T][3072] v-part -> vt bf16 [b*h][d=64][t=2048]
// ---------------------------------------------------------------------------
__global__ __launch_bounds__(256) void vtrans_kernel(
    const bf16_t* __restrict__ qkv, bf16_t* __restrict__ vt) {
  __shared__ bf16_t tile[32][33];
  int tx = threadIdx.x, ty = threadIdx.y;  // (32,8)
  int t0 = blockIdx.x * 32;
  int d0 = (blockIdx.y & 1) * 32;
  int bh = blockIdx.y >> 1;
  int b = bh >> 4, hh = bh & 15;
#pragma unroll
  for (int i = 0; i < 32; i += 8)
    tile[ty + i][tx] =
        qkv[(long)(b * T_ + t0 + ty + i) * LDQ_ + 2 * E_ + hh * HS_ + d0 + tx];
  __syncthreads();
#pragma unroll
  for (int i = 0; i < 32; i += 8)
    vt[((long)bh * HS_ + d0 + ty + i) * T_ + t0 + tx] = tile[tx][ty + i];
}

// ---------------------------------------------------------------------------
// Causal flash attention, KV-split, no-max softmax. S^T form.
// r6: RING-3 + counted vmcnt + raw s_barrier (the GEMM r3 structure).
// r5 diagnosis: __syncthreads drains vmcnt(0) for the prefetch issued the
// SAME iteration -> compute window (~800cy) < HBM/L3 latency -> every one of
// the 8704 barriers ate the residual latency. Now: statically-named 3-deep
// ring (K0s..K2s / V0s..V2s; r2 lesson: runtime-indexed buffers defeat the
// waitcnt pass's alias analysis -> forced drains). Iter j: issue stage(j+2),
// compute tile j, s_waitcnt vmcnt(4) (tile j+1 landed; j+2 in flight), raw
// s_barrier. Each tile gets TWO full iterations to land. KVBLK=64; LDS
// 6x8KB + 8KB Ps = 56KB -> 2 blocks/CU. Barrier is drain-free.
// Split bookkeeping: r3's (12 x 64-kv iters per split chunk, 30 blocks/bh).
// ---------------------------------------------------------------------------
__global__ __launch_bounds__(256) void flash_attn_kernel(
    const bf16_t* __restrict__ qkv, const bf16_t* __restrict__ vt,
    bf16_t* __restrict__ attn, bf16_t* __restrict__ Opart,
    float* __restrict__ mlpart) {
  int gx = blockIdx.x;
  int ti = 0, sp = 0;
  for (int t = 0; t < 16; ++t) {
    int ns = t / 6 + 1;
    if (gx < ns) { ti = t; sp = gx; break; }
    gx -= ns;
  }
  const int nsplit = ti / 6 + 1;
  const int totIt = 2 * (ti + 1);
  const int jbeg = 12 * sp;
  const int jend = min(jbeg + 12, totIt);

  const int tid = threadIdx.x;
  const int lane = tid & 63, wave = tid >> 6;
  const int quad = lane >> 4, l16 = lane & 15;
  const int bh = blockIdx.y, b = bh >> 4, hh = bh & 15;
  const int q0 = ti * 128;
  const int qw = q0 + wave * 32;

  // 3-deep ring, statically named (alias-analysis-proof)
  __shared__ __align__(16) bf16_t K0s[64 * 64], K1s[64 * 64], K2s[64 * 64];
  __shared__ __align__(16) bf16_t V0s[64 * 64], V1s[64 * 64], V2s[64 * 64];
  __shared__ __align__(16) bf16_t Ps[4][16 * 64];  // per-wave P^T, swizzled

  const bf16_t* qb = qkv;
  const bf16_t* kb = qkv + E_;

  // Q fragments, pre-scaled by HS^-0.5 = 0.125 (power of 2: exact in bf16)
  bf16x8 aq[2][2];
#pragma unroll
  for (int s = 0; s < 2; ++s) {
    long base = (long)(b * T_ + qw + s * 16 + l16) * LDQ_ + hh * HS_ + quad * 8;
    aq[s][0] = *(const bf16x8*)&qb[base];
    aq[s][1] = *(const bf16x8*)&qb[base + 32];
#pragma unroll
    for (int e = 0; e < 8; ++e) {
      aq[s][0][e] = (bf16_t)((float)aq[s][0][e] * 0.125f);
      aq[s][1][e] = (bf16_t)((float)aq[s][1][e] * 0.125f);
    }
  }

  f32x4 o[2][4] = {};     // O^T accumulator: [s][nt]; row d=quad*4+r, col q=l16
  float lsum[2] = {};     // per-lane row sums (q = qs + l16)

  // async stage of one K tile [64][64] + V^T tile [64][64] into (Kd, Vd).
  // LDS dest linear; chunk-XOR swizzle applied on the per-lane GLOBAL source.
  // 4 loads per thread per stage.
  auto stage = [&](bf16_t* Kd, bf16_t* Vd, int j) {
    const int kv0 = j * 64;
#pragma unroll
    for (int i = 0; i < 2; ++i) {
      int c = i * 256 + tid;
      int row = c >> 3;                      // 0..63
      int gcol = ((c & 7) ^ (row & 7)) * 8;  // swizzled 16B chunk
      gload_lds16(&kb[(long)(b * T_ + kv0 + row) * LDQ_ + hh * HS_ + gcol],
                  Kd + (i * 256 + wave * 64) * 8);
      gload_lds16(&vt[((long)bh * HS_ + row) * T_ + kv0 + gcol],
                  Vd + (i * 256 + wave * 64) * 8);
    }
  };

  // one ring step: compute tile j from (KsL,VsL); prefetch j+2 into (pK,pV).
  auto step = [&](int j, const bf16_t* KsL, const bf16_t* VsL, bf16_t* pK,
                  bf16_t* pV) {
    if (j + 2 < jend) stage(pK, pV, j + 2);
    const int kv0 = j * 64;
    bf16_t* Pw = Ps[wave];

#pragma unroll
    for (int s = 0; s < 2; ++s) {
      const int qs = qw + s * 16;
      if (kv0 <= qs + 15) {
        // ---- S^T = K * Q^T : rows kv (quad*4+r per sub), col q (l16) ----
        f32x4 sc[4];
        __builtin_amdgcn_s_setprio(1);
#pragma unroll
        for (int sub = 0; sub < 4; ++sub) {
          const int rk = sub * 16 + l16;
          const int k0 = rk * 64 + ((quad ^ (rk & 7)) * 8);
          f32x4 t = {};
          t = __builtin_amdgcn_mfma_f32_16x16x32_bf16(
              *(const bf16x8*)&KsL[k0], aq[s][0], t, 0, 0, 0);
          t = __builtin_amdgcn_mfma_f32_16x16x32_bf16(
              *(const bf16x8*)&KsL[k0 ^ 32], aq[s][1], t, 0, 0, 0);
          sc[sub] = t;
        }
        __builtin_amdgcn_s_setprio(0);
        // ---- causal mask (diagonal tiles only): kv > q -> -inf ----
        if (kv0 + 63 > qs) {
          int qcol = qs + l16;
#pragma unroll
          for (int sub = 0; sub < 4; ++sub)
#pragma unroll
            for (int r = 0; r < 4; ++r) {
              int kvrow = kv0 + sub * 16 + quad * 4 + r;
              if (kvrow > qcol) sc[sub][r] = -INFINITY;
            }
        }
        // ---- p = exp(s); l accumulates per-lane ----
        float part = 0.f;
#pragma unroll
        for (int sub = 0; sub < 4; ++sub) {
#pragma unroll
          for (int r = 0; r < 4; ++r) sc[sub][r] = __expf(sc[sub][r]);
          part += (sc[sub][0] + sc[sub][1]) + (sc[sub][2] + sc[sub][3]);
        }
        lsum[s] += part;
        // ---- P^T -> LDS (swizzled): 4 consecutive kv per lane -> b64 ----
#pragma unroll
        for (int sub = 0; sub < 4; ++sub) {
          bf16x4 pk;
#pragma unroll
          for (int r = 0; r < 4; ++r) pk[r] = (bf16_t)sc[sub][r];
          const int ch = sub * 2 + (quad >> 1);
          const int off = ((ch ^ (l16 & 7)) * 8) + ((quad & 1) * 4);
          *(bf16x4*)&Pw[l16 * 64 + off] = pk;
        }
        // ---- O^T += V^T * P^T (intra-wave, no barrier) ----
        const int p0 = l16 * 64 + ((quad ^ (l16 & 7)) * 8);
        bf16x8 ap0 = *(const bf16x8*)&Pw[p0];
        bf16x8 ap1 = *(const bf16x8*)&Pw[p0 ^ 32];
        __builtin_amdgcn_s_setprio(1);
#pragma unroll
        for (int nt = 0; nt < 4; ++nt) {
          const int rv = nt * 16 + l16;
          const int v0 = rv * 64 + ((quad ^ (rv & 7)) * 8);
          o[s][nt] = __builtin_amdgcn_mfma_f32_16x16x32_bf16(
              *(const bf16x8*)&VsL[v0], ap0, o[s][nt], 0, 0, 0);
          o[s][nt] = __builtin_amdgcn_mfma_f32_16x16x32_bf16(
              *(const bf16x8*)&VsL[v0 ^ 32], ap1, o[s][nt], 0, 0, 0);
        }
        __builtin_amdgcn_s_setprio(0);
      }
    }
    // counted wait: tile j+1 must have landed (its 4 loads); tile j+2's 4
    // may stay in flight. Then drain-free barrier: protects next iter's
    // prefetch (into the buffer just computed on) against current readers,
    // and publishes every wave's j+1 loads.
    if (j + 2 < jend)
      asm volatile("s_waitcnt vmcnt(4)" ::: "memory");
    else if (j + 1 < jend)
      asm volatile("s_waitcnt vmcnt(0)" ::: "memory");
    if (j + 1 < jend) __builtin_amdgcn_s_barrier();
  };

  // prologue: stage tiles jbeg, jbeg+1; wait for the first (second may fly)
  stage(K0s, V0s, jbeg);
  if (jbeg + 1 < jend) {
    stage(K1s, V1s, jbeg + 1);
    asm volatile("s_waitcnt vmcnt(4)" ::: "memory");
  } else {
    asm volatile("s_waitcnt vmcnt(0)" ::: "memory");
  }
  __builtin_amdgcn_s_barrier();

  int j = jbeg;
  while (true) {
    step(j, K0s, V0s, K2s, V2s); if (++j >= jend) break;
    step(j, K1s, V1s, K0s, V0s); if (++j >= jend) break;
    step(j, K2s, V2s, K1s, V1s); if (++j >= jend) break;
  }

  // ---- l reduction across the 4 quads sharing each q ----
  float lval[2];
#pragma unroll
  for (int s = 0; s < 2; ++s) {
    float v = lsum[s];
    v += __shfl_xor(v, 16);
    v += __shfl_xor(v, 32);
    lval[s] = v;
  }

  if (nsplit == 1) {
#pragma unroll
    for (int s = 0; s < 2; ++s) {
      float inv = 1.f / lval[s];
      long rowg = (long)b * T_ + qw + s * 16 + l16;
#pragma unroll
      for (int nt = 0; nt < 4; ++nt) {
        bf16x4 pk;
#pragma unroll
        for (int r = 0; r < 4; ++r) pk[r] = (bf16_t)(o[s][nt][r] * inv);
        *(bf16x4*)&attn[rowg * E_ + hh * HS_ + nt * 16 + quad * 4] = pk;
      }
    }
  } else {
    int idx = (ti < 12) ? (ti - 6) * 2 + sp : 12 + (ti - 12) * 3 + sp;
    long slot = (long)bh * 24 + idx;
    bf16_t* op = Opart + slot * (128 * 64);
    float* ml = mlpart + slot * 256;
#pragma unroll
    for (int s = 0; s < 2; ++s) {
      float inv = 1.f / lval[s];
      int rloc = wave * 32 + s * 16 + l16;
#pragma unroll
      for (int nt = 0; nt < 4; ++nt) {
        bf16x4 pk;
#pragma unroll
        for (int r = 0; r < 4; ++r) pk[r] = (bf16_t)(o[s][nt][r] * inv);
        *(bf16x4*)&op[rloc * 64 + nt * 16 + quad * 4] = pk;
      }
      if (quad == 0) ml[rloc] = lval[s];
    }
  }
}

// ---------------------------------------------------------------------------
// Merge partials for multi-split q-tiles (ti = 6..15): O = sum(l_s*Ohat_s)/sum(l_s)
// grid: (10, 64bh), 256 threads: thread = row(128) * 2 + d-half(32).
// ---------------------------------------------------------------------------
__global__ __launch_bounds__(256) void flash_merge_kernel(
    const bf16_t* __restrict__ Opart, const float* __restrict__ mlpart,
    bf16_t* __restrict__ attn) {
  int ti = 6 + blockIdx.x;
  int bh = blockIdx.y, b = bh >> 4, hh = bh & 15;
  int ns = ti / 6 + 1;
  int base_idx = (ti < 12) ? (ti - 6) * 2 : 12 + (ti - 12) * 3;
  int r = threadIdx.x >> 1;
  int dh = (threadIdx.x & 1) * 32;

  float w[3], den = 0.f;
  for (int s = 0; s < ns; ++s) {
    long slot = (long)bh * 24 + base_idx + s;
    w[s] = mlpart[slot * 256 + r];
    den += w[s];
  }
  float inv = 1.f / den;
  float acc[32];
#pragma unroll
  for (int d = 0; d < 32; ++d) acc[d] = 0.f;
  for (int s = 0; s < ns; ++s) {
    long slot = (long)bh * 24 + base_idx + s;
    const bf16_t* op = Opart + slot * (128 * 64) + r * 64 + dh;
#pragma unroll
    for (int d = 0; d < 32; ++d) acc[d] += w[s] * (float)op[d];
  }
  long rowg = (long)b * T_ + ti * 128 + r;
  bf16_t* dst = attn + rowg * E_ + hh * HS_ + dh;
#pragma unroll
  for (int d = 0; d < 32; ++d) dst[d] = (bf16_t)(acc[d] * inv);
}

// ---------------------------------------------------------------------------
extern "C" void kernel_launch(void* const* d_in, const int* in_sizes, int n_in,
                              void* d_out, int out_size, void* d_ws,
                              size_t ws_size, hipStream_t stream) {
  const float* x = (const float*)d_in[0];
  const float* ln1_g = (const float*)d_in[1];
  const float* ln1_b = (const float*)d_in[2];
  const float* Wq = (const float*)d_in[3];
  const float* bq = (const float*)d_in[4];
  const float* Wk = (const float*)d_in[5];
  const float* bk = (const float*)d_in[6];
  const float* Wv = (const float*)d_in[7];
  const float* bv = (const float*)d_in[8];
  const float* Wp = (const float*)d_in[9];
  const float* bp = (const float*)d_in[10];
  const float* ln2_g = (const float*)d_in[11];
  const float* ln2_b = (const float*)d_in[12];
  const float* W1 = (const float*)d_in[13];
  const float* b1 = (const float*)d_in[14];
  const float* W2 = (const float*)d_in[15];
  const float* b2 = (const float*)d_in[16];
  float* out = (float*)d_out;

  const size_t MB = 1ull << 20;
  char* ws = (char*)d_ws;
  bf16_t* wqkvt = (bf16_t*)(ws + 0 * MB);   // [3072][1024] bf16 = 6 MB
  bf16_t* wpt   = (bf16_t*)(ws + 6 * MB);   // 2 MB
  bf16_t* w1t   = (bf16_t*)(ws + 8 * MB);   // 8 MB
  bf16_t* w2t   = (bf16_t*)(ws + 16 * MB);  // 8 MB
  float*  bqkv  = (float*)(ws + 24 * MB);   // 12 KB
  bf16_t* h     = (bf16_t*)(ws + 25 * MB);  // [8192][1024] 16 MB; reused: attn, h2
  bf16_t* qkvb  = (bf16_t*)(ws + 41 * MB);  // [8192][3072] 48 MB; reused: ff1
  bf16_t* vt    = (bf16_t*)(ws + 89 * MB);  // [64][64][2048] 16 MB
  float*  xmid  = (float*)(ws + 105 * MB);  // 32 MB -> ends 137 MB
  // flash scratch overlaps xmid temporally (dead before proj writes xmid):
  bf16_t* Opart = (bf16_t*)(ws + 105 * MB); // 1536 slots * 8192 bf16 = 25.2 MB
  float* mlpart = (float*)(ws + 131 * MB);  // 1536 * 256 fp32 = 1.5 MB
  bf16_t* attn  = h;                        // h dead after QKV gemm
  bf16_t* h2    = h;                        // attn dead after proj gemm
  bf16_t* ff1   = qkvb;                     // qkv+vt dead after flash

  dim3 tb(32, 8);
  // weight transposes into fused QKV layout [3072][1024]
  wtrans_kernel<<<dim3(E_ / 32, E_ / 32), tb, 0, stream>>>(Wq, wqkvt, E_, E_);
  wtrans_kernel<<<dim3(E_ / 32, E_ / 32), tb, 0, stream>>>(Wk, wqkvt + (long)E_ * E_, E_, E_);
  wtrans_kernel<<<dim3(E_ / 32, E_ / 32), tb, 0, stream>>>(Wv, wqkvt + 2l * E_ * E_, E_, E_);
  wtrans_kernel<<<dim3(E_ / 32, E_ / 32), tb, 0, stream>>>(Wp, wpt, E_, E_);
  wtrans_kernel<<<dim3(DFF_ / 32, E_ / 32), tb, 0, stream>>>(W1, w1t, E_, DFF_);
  wtrans_kernel<<<dim3(E_ / 32, DFF_ / 32), tb, 0, stream>>>(W2, w2t, DFF_, E_);
  bcat_kernel<<<12, 256, 0, stream>>>(bq, bk, bv, bqkv);

  // LN1
  layernorm_kernel<<<M_, 256, 0, stream>>>(x, ln1_g, ln1_b, h);

  // fused QKV gemm: [8192][3072], 256x128 tiles -> 768 blocks = 3/CU exact
  gemm256x128_kernel<0><<<dim3(3 * E_ / 128, M_ / 256), 512, 0, stream>>>(
      h, wqkvt, bqkv, nullptr, qkvb, 3 * E_, E_);

  // V transpose to [bh][d][t]
  vtrans_kernel<<<dim3(T_ / 32, 2 * B_ * H_), tb, 0, stream>>>(qkvb, vt);

  // flash attention, KV-split (30 uniform blocks per bh) + merge
  flash_attn_kernel<<<dim3(30, B_ * H_), 256, 0, stream>>>(qkvb, vt, attn,
                                                           Opart, mlpart);
  flash_merge_kernel<<<dim3(10, B_ * H_), 256, 0, stream>>>(Opart, mlpart, attn);

  // proj + residual -> xmid (fp32), 256x128 tiles -> 256 blocks = 1/CU
  gemm256x128_kernel<1><<<dim3(E_ / 128, M_ / 256), 512, 0, stream>>>(
      attn, wpt, bp, x, xmid, E_, E_);

  // LN2
  layernorm_kernel<<<M_, 256, 0, stream>>>(xmid, ln2_g, ln2_b, h2);

  // FFN: FF1 [8192][4096] on 256x256 path (relu, 512 blk = 2/CU exact);
  // FF2 [8192][1024] K=4096 on 256x128 path (+resid, fp32 out)
  gemm256_kernel<1><<<dim3(DFF_ / 256, M_ / 256), 512, 0, stream>>>(
      h2, w1t, b1, ff1, DFF_, E_);
  gemm256x128_kernel<1><<<dim3(E_ / 128, M_ / 256), 512, 0, stream>>>(
      ff1, w2t, b2, xmid, out, E_, DFF_);
}

// Round 7
// 512.324 us; speedup vs baseline: 1.0313x; 1.0313x over previous
//
#include <hip/hip_runtime.h>
#include <hip/hip_bf16.h>

#define B_ 4
#define T_ 2048
#define E_ 1024
#define H_ 16
#define HS_ 64
#define DFF_ 4096
#define M_ (B_ * T_)   // 8192 tokens
#define LDQ_ (3 * E_)  // qkv fused row stride

typedef __bf16 bf16_t;
typedef __bf16 bf16x4 __attribute__((ext_vector_type(4)));
typedef __bf16 bf16x8 __attribute__((ext_vector_type(8)));
typedef float f32x4 __attribute__((ext_vector_type(4)));

#define AS1 __attribute__((address_space(1)))
#define AS3 __attribute__((address_space(3)))

__device__ __forceinline__ void gload_lds16(const void* g, void* l) {
  __builtin_amdgcn_global_load_lds((AS1 void*)(g), (AS3 void*)(l), 16, 0, 0);
}

// ---------------------------------------------------------------------------
// Weight convert+transpose: W fp32 [Krows][Ncols] -> Wt bf16 [Ncols][Krows]
// ---------------------------------------------------------------------------
__global__ __launch_bounds__(256) void wtrans_kernel(
    const float* __restrict__ W, bf16_t* __restrict__ Wt, int Krows, int Ncols) {
  __shared__ float tile[32][33];
  int tx = threadIdx.x, ty = threadIdx.y;  // (32,8)
  int n0 = blockIdx.x * 32, k0 = blockIdx.y * 32;
#pragma unroll
  for (int i = 0; i < 32; i += 8)
    tile[ty + i][tx] = W[(long)(k0 + ty + i) * Ncols + n0 + tx];
  __syncthreads();
#pragma unroll
  for (int i = 0; i < 32; i += 8)
    Wt[(long)(n0 + ty + i) * Krows + k0 + tx] = (bf16_t)tile[tx][ty + i];
}

// bias concat: [bq | bk | bv] -> 3072 floats
__global__ __launch_bounds__(256) void bcat_kernel(const float* a, const float* b,
                                                   const float* c, float* o) {
  int i = blockIdx.x * 256 + threadIdx.x;
  o[i] = i < 1024 ? a[i] : (i < 2048 ? b[i - 1024] : c[i - 2048]);
}

// ---------------------------------------------------------------------------
// LayerNorm: fp32 [M][1024] -> bf16 [M][1024]
// ---------------------------------------------------------------------------
__global__ __launch_bounds__(256) void layernorm_kernel(
    const float* __restrict__ in, const float* __restrict__ g,
    const float* __restrict__ b, bf16_t* __restrict__ out) {
  int row = blockIdx.x;
  int tid = threadIdx.x;
  const float4* inr = (const float4*)(in + (long)row * E_);
  float4 v = inr[tid];
  float s = v.x + v.y + v.z + v.w;
  float ss = v.x * v.x + v.y * v.y + v.z * v.z + v.w * v.w;
#pragma unroll
  for (int o = 32; o; o >>= 1) {
    s += __shfl_xor(s, o);
    ss += __shfl_xor(ss, o);
  }
  __shared__ float red[8];
  int wv = tid >> 6;
  if ((tid & 63) == 0) {
    red[wv] = s;
    red[4 + wv] = ss;
  }
  __syncthreads();
  s = red[0] + red[1] + red[2] + red[3];
  ss = red[4] + red[5] + red[6] + red[7];
  float mu = s * (1.f / E_);
  float var = ss * (1.f / E_) - mu * mu;
  float rs = rsqrtf(var + 1e-5f);
  int ci = tid * 4;
  float4 gv = *(const float4*)(g + ci);
  float4 bv = *(const float4*)(b + ci);
  long o0 = (long)row * E_ + ci;
  out[o0 + 0] = (bf16_t)((v.x - mu) * rs * gv.x + bv.x);
  out[o0 + 1] = (bf16_t)((v.y - mu) * rs * gv.y + bv.y);
  out[o0 + 2] = (bf16_t)((v.z - mu) * rs * gv.z + bv.z);
  out[o0 + 3] = (bf16_t)((v.w - mu) * rs * gv.w + bv.w);
}

// ---------------------------------------------------------------------------
// GEMM (256x256 path, FF1): BK=32, 8 waves (2Mx4N, per-wave 128x64),
// 4-deep ring of K-tiles in statically-named LDS slots (alias-analysis-proof:
// r2 lesson), counted vmcnt, loop unrolled x4. K % 128 == 0.
// RELU 0: bf16 + bias; RELU 1: bf16 relu(+bias).
// ---------------------------------------------------------------------------
template <int RELU>
__global__ __launch_bounds__(512, 2) void gemm256_kernel(
    const bf16_t* __restrict__ A, const bf16_t* __restrict__ Bt,
    const float* __restrict__ bias, bf16_t* __restrict__ out, int N, int K) {
  __shared__ bf16_t As0[256 * 32], As1[256 * 32], As2[256 * 32], As3[256 * 32];
  __shared__ bf16_t Bs0[256 * 32], Bs1[256 * 32], Bs2[256 * 32], Bs3[256 * 32];
  const int tid = threadIdx.x;
  const int wave = tid >> 6;  // 0..7
  const int lane = tid & 63;
  const int wr = wave >> 2;   // 0..1 : row half (128 rows)
  const int wc = wave & 3;    // 0..3 : col quarter (64 cols)
  const int quad = lane >> 4, l16 = lane & 15;

  const int gx = gridDim.x;
  const int id = blockIdx.y * gx + blockIdx.x;
  const int xcd = id & 7;
  const int k_ = id >> 3;
  const int bxr = k_ % gx;
  const int byr = (k_ / gx) * 8 + xcd;
  const long rowBase = (long)byr * 256;
  const long colBase = (long)bxr * 256;

  f32x4 acc[8][4] = {};  // [mh*4+fr][fc]

  const int ntiles = K >> 5;  // multiple of 4

  auto stageA = [&](bf16_t* dst, int t) {
    const int k0 = t << 5;
#pragma unroll
    for (int p = 0; p < 2; ++p) {
      int idx = p * 512 + tid;  // chunk id 0..1023
      int row = idx >> 2;       // 0..255
      int col = (idx & 3) * 8;  // 0,8,16,24
      gload_lds16(&A[(rowBase + row) * K + k0 + col],
                  dst + (p * 512 + wave * 64) * 8);
    }
  };
  auto stageB = [&](bf16_t* dst, int t) {
    const int k0 = t << 5;
#pragma unroll
    for (int p = 0; p < 2; ++p) {
      int idx = p * 512 + tid;
      int row = idx >> 2;
      int col = (idx & 3) * 8;
      gload_lds16(&Bt[(colBase + row) * K + k0 + col],
                  dst + (p * 512 + wave * 64) * 8);
    }
  };

  auto tileStep = [&](int t, const bf16_t* as, const bf16_t* bs, bf16_t* nA,
                      bf16_t* nB) {
    const bool pre = (t + 3 < ntiles);
    bf16x8 bfrag[4];
#pragma unroll
    for (int fc = 0; fc < 4; ++fc)
      bfrag[fc] = *(const bf16x8*)&bs[(wc * 64 + fc * 16 + l16) * 32 + quad * 8];

    // ---- phase 0: row-half mh=0 ----
    {
      bf16x8 afrag[4];
#pragma unroll
      for (int fr = 0; fr < 4; ++fr)
        afrag[fr] =
            *(const bf16x8*)&as[(wr * 128 + fr * 16 + l16) * 32 + quad * 8];
      if (pre) stageA(nA, t + 3);
      __builtin_amdgcn_s_setprio(1);
#pragma unroll
      for (int fr = 0; fr < 4; ++fr)
#pragma unroll
        for (int fc = 0; fc < 4; ++fc)
          acc[fr][fc] = __builtin_amdgcn_mfma_f32_16x16x32_bf16(
              afrag[fr], bfrag[fc], acc[fr][fc], 0, 0, 0);
      __builtin_amdgcn_s_setprio(0);
      __builtin_amdgcn_s_barrier();
    }
    // ---- phase 1: row-half mh=1 ----
    {
      bf16x8 afrag[4];
#pragma unroll
      for (int fr = 0; fr < 4; ++fr)
        afrag[fr] = *(const bf16x8*)&as[(wr * 128 + 64 + fr * 16 + l16) * 32 +
                                        quad * 8];
      if (pre) stageB(nB, t + 3);
      __builtin_amdgcn_s_setprio(1);
#pragma unroll
      for (int fr = 0; fr < 4; ++fr)
#pragma unroll
        for (int fc = 0; fc < 4; ++fc)
          acc[4 + fr][fc] = __builtin_amdgcn_mfma_f32_16x16x32_bf16(
              afrag[fr], bfrag[fc], acc[4 + fr][fc], 0, 0, 0);
      __builtin_amdgcn_s_setprio(0);
      if (t + 3 < ntiles)
        asm volatile("s_waitcnt vmcnt(8)" ::: "memory");
      else if (t + 2 < ntiles)
        asm volatile("s_waitcnt vmcnt(4)" ::: "memory");
      else if (t + 1 < ntiles)
        asm volatile("s_waitcnt vmcnt(0)" ::: "memory");
      if (t + 1 < ntiles) __builtin_amdgcn_s_barrier();
    }
  };

  stageA(As0, 0); stageB(Bs0, 0);
  stageA(As1, 1); stageB(Bs1, 1);
  stageA(As2, 2); stageB(Bs2, 2);
  asm volatile("s_waitcnt vmcnt(8)" ::: "memory");
  __builtin_amdgcn_s_barrier();

  for (int t = 0; t < ntiles; t += 4) {
    tileStep(t + 0, As0, Bs0, As3, Bs3);
    tileStep(t + 1, As1, Bs1, As0, Bs0);
    tileStep(t + 2, As2, Bs2, As1, Bs1);
    tileStep(t + 3, As3, Bs3, As2, Bs2);
  }

#pragma unroll
  for (int mh = 0; mh < 2; ++mh)
#pragma unroll
    for (int fr = 0; fr < 4; ++fr)
#pragma unroll
      for (int fc = 0; fc < 4; ++fc) {
        int colg = (int)colBase + wc * 64 + fc * 16 + l16;
        float bv = bias[colg];
#pragma unroll
        for (int r = 0; r < 4; ++r) {
          long rowg = rowBase + wr * 128 + mh * 64 + fr * 16 + quad * 4 + r;
          float v = acc[mh * 4 + fr][fc][r] + bv;
          if (RELU) v = fmaxf(v, 0.f);
          out[rowg * N + colg] = (bf16_t)v;
        }
      }
}

// ---------------------------------------------------------------------------
// GEMM (256x128 path, QKV/proj/FF2): 8 waves (4r x 2c, per-wave 64x64),
// named-slot 4-deep ring + counted vmcnt. LDS 96KB, 1 block/CU.
// 3 loads per K-tile -> steady-state vmcnt(6). K % 128 == 0.
// MODE 0: bf16 C+bias; MODE 1: fp32 C+bias+resid;
// MODE 2: bf16 C+bias AND mirror V columns (colg>=2048) into vt[bh][d][t]
//         (fuses the old vtrans kernel into the QKV epilogue; stores are
//         coalesced in t since the inner r-loop walks consecutive rows).
// ---------------------------------------------------------------------------
template <int MODE>
__global__ __launch_bounds__(512, 1) void gemm256x128_kernel(
    const bf16_t* __restrict__ A, const bf16_t* __restrict__ Bt,
    const float* __restrict__ bias, const float* __restrict__ resid,
    void* __restrict__ out, bf16_t* __restrict__ vt_out, int N, int K) {
  __shared__ bf16_t As0[256 * 32], As1[256 * 32], As2[256 * 32], As3[256 * 32];
  __shared__ bf16_t Bs0[128 * 32], Bs1[128 * 32], Bs2[128 * 32], Bs3[128 * 32];
  const int tid = threadIdx.x;
  const int wave = tid >> 6;  // 0..7
  const int lane = tid & 63;
  const int wr = wave >> 1;   // 0..3 : 64-row band
  const int wc = wave & 1;    // 0..1 : 64-col half
  const int quad = lane >> 4, l16 = lane & 15;

  const int gx = gridDim.x;
  const int id = blockIdx.y * gx + blockIdx.x;
  const int xcd = id & 7;
  const int k_ = id >> 3;
  const int bxr = k_ % gx;
  const int byr = (k_ / gx) * 8 + xcd;
  const long rowBase = (long)byr * 256;
  const long colBase = (long)bxr * 128;

  f32x4 acc[4][4] = {};  // [fr][fc]

  const int ntiles = K >> 5;  // multiple of 4

  auto stageA = [&](bf16_t* dst, int t) {
    const int k0 = t << 5;
#pragma unroll
    for (int p = 0; p < 2; ++p) {
      int idx = p * 512 + tid;
      int row = idx >> 2;       // 0..255
      int col = (idx & 3) * 8;  // 0,8,16,24
      gload_lds16(&A[(rowBase + row) * K + k0 + col],
                  dst + (p * 512 + wave * 64) * 8);
    }
  };
  auto stageB = [&](bf16_t* dst, int t) {
    const int k0 = t << 5;
    int row = tid >> 2;       // 0..127
    int col = (tid & 3) * 8;  // 0,8,16,24
    gload_lds16(&Bt[(colBase + row) * K + k0 + col], dst + (wave * 64) * 8);
  };

  auto tileStep = [&](int t, const bf16_t* as, const bf16_t* bs, bf16_t* nA,
                      bf16_t* nB) {
    const bool pre = (t + 3 < ntiles);
    bf16x8 bfrag[4];
#pragma unroll
    for (int fc = 0; fc < 4; ++fc)
      bfrag[fc] = *(const bf16x8*)&bs[(wc * 64 + fc * 16 + l16) * 32 + quad * 8];

    // ---- phase 0: rows fr=0,1 ----
    {
      bf16x8 afrag[2];
#pragma unroll
      for (int fr = 0; fr < 2; ++fr)
        afrag[fr] =
            *(const bf16x8*)&as[(wr * 64 + fr * 16 + l16) * 32 + quad * 8];
      if (pre) stageA(nA, t + 3);
      __builtin_amdgcn_s_setprio(1);
#pragma unroll
      for (int fr = 0; fr < 2; ++fr)
#pragma unroll
        for (int fc = 0; fc < 4; ++fc)
          acc[fr][fc] = __builtin_amdgcn_mfma_f32_16x16x32_bf16(
              afrag[fr], bfrag[fc], acc[fr][fc], 0, 0, 0);
      __builtin_amdgcn_s_setprio(0);
      __builtin_amdgcn_s_barrier();
    }
    // ---- phase 1: rows fr=2,3 ----
    {
      bf16x8 afrag[2];
#pragma unroll
      for (int fr = 2; fr < 4; ++fr)
        afrag[fr - 2] =
            *(const bf16x8*)&as[(wr * 64 + fr * 16 + l16) * 32 + quad * 8];
      if (pre) stageB(nB, t + 3);
      __builtin_amdgcn_s_setprio(1);
#pragma unroll
      for (int fr = 2; fr < 4; ++fr)
#pragma unroll
        for (int fc = 0; fc < 4; ++fc)
          acc[fr][fc] = __builtin_amdgcn_mfma_f32_16x16x32_bf16(
              afrag[fr - 2], bfrag[fc], acc[fr][fc], 0, 0, 0);
      __builtin_amdgcn_s_setprio(0);
      if (t + 3 < ntiles)
        asm volatile("s_waitcnt vmcnt(6)" ::: "memory");
      else if (t + 2 < ntiles)
        asm volatile("s_waitcnt vmcnt(3)" ::: "memory");
      else if (t + 1 < ntiles)
        asm volatile("s_waitcnt vmcnt(0)" ::: "memory");
      if (t + 1 < ntiles) __builtin_amdgcn_s_barrier();
    }
  };

  stageA(As0, 0); stageB(Bs0, 0);
  stageA(As1, 1); stageB(Bs1, 1);
  stageA(As2, 2); stageB(Bs2, 2);
  asm volatile("s_waitcnt vmcnt(6)" ::: "memory");
  __builtin_amdgcn_s_barrier();

  for (int t = 0; t < ntiles; t += 4) {
    tileStep(t + 0, As0, Bs0, As3, Bs3);
    tileStep(t + 1, As1, Bs1, As0, Bs0);
    tileStep(t + 2, As2, Bs2, As1, Bs1);
    tileStep(t + 3, As3, Bs3, As2, Bs2);
  }

#pragma unroll
  for (int fr = 0; fr < 4; ++fr)
#pragma unroll
    for (int fc = 0; fc < 4; ++fc) {
      int colg = (int)colBase + wc * 64 + fc * 16 + l16;
      float bv = bias[colg];
#pragma unroll
      for (int r = 0; r < 4; ++r) {
        long rowg = rowBase + wr * 64 + fr * 16 + quad * 4 + r;
        float v = acc[fr][fc][r] + bv;
        long idx = rowg * N + colg;
        if (MODE == 1) {
          ((float*)out)[idx] = v + resid[idx];
        } else {
          ((bf16_t*)out)[idx] = (bf16_t)v;
          if (MODE == 2 && colg >= 2 * E_) {
            int d = colg & 63;
            int hh2 = (colg - 2 * E_) >> 6;
            int bb = (int)(rowg >> 11);      // T_ = 2048
            int tt = (int)(rowg & 2047);
            vt_out[(((long)(bb * 16 + hh2)) * 64 + d) * T_ + tt] = (bf16_t)v;
          }
        }
      }
    }
}

// ---------------------------------------------------------------------------
// Causal flash attention, KV-split, no-max softmax. S^T form.
// r7: PAIRED Q-TILES -- 512 threads / 8 waves; waves 0-3 own q-tile 2pt,
// waves 4-7 own 2pt+1, SHARING one K/V staging (r3's best-measured dbuf +
// __syncthreads, KVBLK=64). Rationale: occupancy was pinned ~22% across all
// r3-r6 staging variants (TLP-starved, no pipe >45%); pairing doubles
// waves/block, halves barrier count per unit work, and halves K/V HBM
// traffic. Structural invariants (verified): nsplit(2pt)==nsplit(2pt+1) for
// every pair (ti/6 increments only at even ti); the causal check
// kv0<=qs+15 automatically idles lower-tile waves past their extent; every
// sub-tile computes >=1 iter (768sp <= 256pt <= qs) so no 1/0 in the
// normalization. Grid 15x64 (was 30x64), reversed decode so long blocks
// dispatch first. LDS = 2x8K(K) + 2x8K(V) + 16K(Ps) = 48KB.
// Split/merge bookkeeping identical per-wave (chunk=12 of kv-64; slot
// mapping unchanged; merge kernel unchanged).
// ---------------------------------------------------------------------------
__global__ __launch_bounds__(512) void flash_attn_kernel(
    const bf16_t* __restrict__ qkv, const bf16_t* __restrict__ vt,
    bf16_t* __restrict__ attn, bf16_t* __restrict__ Opart,
    float* __restrict__ mlpart) {
  int gx = 14 - (int)blockIdx.x;  // reversed: longest pairs first
  int pt = 0, sp = 0;
  for (int p = 0; p < 8; ++p) {
    int ns = (2 * p + 1) / 6 + 1;
    if (gx < ns) { pt = p; sp = gx; break; }
    gx -= ns;
  }

  const int tid = threadIdx.x;
  const int wave = tid >> 6;       // 0..7
  const int half = wave >> 2;      // 0: ti=2pt, 1: ti=2pt+1
  const int wsub = wave & 3;       // 32-row band within the wave's q-tile
  const int lane = tid & 63;
  const int quad = lane >> 4, l16 = lane & 15;
  const int bh = blockIdx.y, b = bh >> 4, hh = bh & 15;

  const int ti = 2 * pt + half;        // this wave's 128-row q-tile
  const int nsplit = ti / 6 + 1;
  const int qw = ti * 128 + wsub * 32;
  const int jbeg = 12 * sp;
  const int jendU = min(12 * sp + 12, 4 * pt + 4);  // union extent (upper)

  __shared__ __align__(16) bf16_t Ks[2][64 * 64];  // [kv][d], chunk-swizzled
  __shared__ __align__(16) bf16_t Vs[2][64 * 64];  // [d][kv], chunk-swizzled
  __shared__ __align__(16) bf16_t Ps[8][16 * 64];  // per-wave P^T, swizzled

  const bf16_t* qb = qkv;
  const bf16_t* kb = qkv + E_;

  // Q fragments, pre-scaled by HS^-0.5 = 0.125 (power of 2: exact in bf16)
  bf16x8 aq[2][2];
#pragma unroll
  for (int s = 0; s < 2; ++s) {
    long base = (long)(b * T_ + qw + s * 16 + l16) * LDQ_ + hh * HS_ + quad * 8;
    aq[s][0] = *(const bf16x8*)&qb[base];
    aq[s][1] = *(const bf16x8*)&qb[base + 32];
#pragma unroll
    for (int e = 0; e < 8; ++e) {
      aq[s][0][e] = (bf16_t)((float)aq[s][0][e] * 0.125f);
      aq[s][1][e] = (bf16_t)((float)aq[s][1][e] * 0.125f);
    }
  }

  f32x4 o[2][4] = {};     // O^T accumulator: [s][nt]; row d=quad*4+r, col q=l16
  float lsum[2] = {};     // per-lane row sums (q = qs + l16)

  // async stage of one K tile [64][64] + V^T tile [64][64] into buffer buf.
  // 512 threads x (1 K-chunk + 1 V-chunk); LDS dest linear (wave-uniform
  // base + lane*16); chunk-XOR swizzle on the per-lane GLOBAL source.
  auto stage = [&](int buf, int j) {
    const int kv0 = j * 64;
    int row = tid >> 3;                      // 0..63
    int gcol = ((tid & 7) ^ (row & 7)) * 8;  // swizzled 16B chunk
    gload_lds16(&kb[(long)(b * T_ + kv0 + row) * LDQ_ + hh * HS_ + gcol],
                &Ks[buf][wave * 512]);
    gload_lds16(&vt[((long)bh * HS_ + row) * T_ + kv0 + gcol],
                &Vs[buf][wave * 512]);
  };

  stage(0, jbeg);
  __syncthreads();

  for (int j = jbeg; j < jendU; ++j) {
    const int kv0 = j * 64;
    const int cur = (j - jbeg) & 1;
    if (j + 1 < jendU) stage(cur ^ 1, j + 1);  // prefetch next KV tile
    const bf16_t* KsL = Ks[cur];
    const bf16_t* VsL = Vs[cur];
    bf16_t* Pw = Ps[wave];

#pragma unroll
    for (int s = 0; s < 2; ++s) {
      const int qs = qw + s * 16;
      if (kv0 <= qs + 15) {
        // ---- S^T = K * Q^T : rows kv (quad*4+r per sub), col q (l16) ----
        f32x4 sc[4];
        __builtin_amdgcn_s_setprio(1);
#pragma unroll
        for (int sub = 0; sub < 4; ++sub) {
          const int rk = sub * 16 + l16;
          const int k0 = rk * 64 + ((quad ^ (rk & 7)) * 8);
          f32x4 t = {};
          t = __builtin_amdgcn_mfma_f32_16x16x32_bf16(
              *(const bf16x8*)&KsL[k0], aq[s][0], t, 0, 0, 0);
          t = __builtin_amdgcn_mfma_f32_16x16x32_bf16(
              *(const bf16x8*)&KsL[k0 ^ 32], aq[s][1], t, 0, 0, 0);
          sc[sub] = t;
        }
        __builtin_amdgcn_s_setprio(0);
        // ---- causal mask (diagonal tiles only): kv > q -> -inf ----
        if (kv0 + 63 > qs) {
          int qcol = qs + l16;
#pragma unroll
          for (int sub = 0; sub < 4; ++sub)
#pragma unroll
            for (int r = 0; r < 4; ++r) {
              int kvrow = kv0 + sub * 16 + quad * 4 + r;
              if (kvrow > qcol) sc[sub][r] = -INFINITY;
            }
        }
        // ---- p = exp(s); l accumulates per-lane ----
        float part = 0.f;
#pragma unroll
        for (int sub = 0; sub < 4; ++sub) {
#pragma unroll
          for (int r = 0; r < 4; ++r) sc[sub][r] = __expf(sc[sub][r]);
          part += (sc[sub][0] + sc[sub][1]) + (sc[sub][2] + sc[sub][3]);
        }
        lsum[s] += part;
        // ---- P^T -> LDS (swizzled): 4 consecutive kv per lane -> b64 ----
#pragma unroll
        for (int sub = 0; sub < 4; ++sub) {
          bf16x4 pk;
#pragma unroll
          for (int r = 0; r < 4; ++r) pk[r] = (bf16_t)sc[sub][r];
          const int ch = sub * 2 + (quad >> 1);
          const int off = ((ch ^ (l16 & 7)) * 8) + ((quad & 1) * 4);
          *(bf16x4*)&Pw[l16 * 64 + off] = pk;
        }
        // ---- O^T += V^T * P^T (intra-wave, no barrier) ----
        const int p0 = l16 * 64 + ((quad ^ (l16 & 7)) * 8);
        bf16x8 ap0 = *(const bf16x8*)&Pw[p0];
        bf16x8 ap1 = *(const bf16x8*)&Pw[p0 ^ 32];
        __builtin_amdgcn_s_setprio(1);
#pragma unroll
        for (int nt = 0; nt < 4; ++nt) {
          const int rv = nt * 16 + l16;
          const int v0 = rv * 64 + ((quad ^ (rv & 7)) * 8);
          o[s][nt] = __builtin_amdgcn_mfma_f32_16x16x32_bf16(
              *(const bf16x8*)&VsL[v0], ap0, o[s][nt], 0, 0, 0);
          o[s][nt] = __builtin_amdgcn_mfma_f32_16x16x32_bf16(
              *(const bf16x8*)&VsL[v0 ^ 32], ap1, o[s][nt], 0, 0, 0);
        }
        __builtin_amdgcn_s_setprio(0);
      }
    }
    __syncthreads();
  }

  // ---- l reduction across the 4 quads sharing each q ----
  float lval[2];
#pragma unroll
  for (int s = 0; s < 2; ++s) {
    float v = lsum[s];
    v += __shfl_xor(v, 16);
    v += __shfl_xor(v, 32);
    lval[s] = v;
  }

  if (nsplit == 1) {
#pragma unroll
    for (int s = 0; s < 2; ++s) {
      float inv = 1.f / lval[s];
      long rowg = (long)b * T_ + qw + s * 16 + l16;
#pragma unroll
      for (int nt = 0; nt < 4; ++nt) {
        bf16x4 pk;
#pragma unroll
        for (int r = 0; r < 4; ++r) pk[r] = (bf16_t)(o[s][nt][r] * inv);
        *(bf16x4*)&attn[rowg * E_ + hh * HS_ + nt * 16 + quad * 4] = pk;
      }
    }
  } else {
    int idx = (ti < 12) ? (ti - 6) * 2 + sp : 12 + (ti - 12) * 3 + sp;
    long slot = (long)bh * 24 + idx;
    bf16_t* op = Opart + slot * (128 * 64);
    float* ml = mlpart + slot * 256;
#pragma unroll
    for (int s = 0; s < 2; ++s) {
      float inv = 1.f / lval[s];
      int rloc = wsub * 32 + s * 16 + l16;
#pragma unroll
      for (int nt = 0; nt < 4; ++nt) {
        bf16x4 pk;
#pragma unroll
        for (int r = 0; r < 4; ++r) pk[r] = (bf16_t)(o[s][nt][r] * inv);
        *(bf16x4*)&op[rloc * 64 + nt * 16 + quad * 4] = pk;
      }
      if (quad == 0) ml[rloc] = lval[s];
    }
  }
}

// ---------------------------------------------------------------------------
// Merge partials for multi-split q-tiles (ti = 6..15): O = sum(l_s*Ohat_s)/sum(l_s)
// grid: (10, 64bh), 256 threads: thread = row(128) * 2 + d-half(32).
// ---------------------------------------------------------------------------
__global__ __launch_bounds__(256) void flash_merge_kernel(
    const bf16_t* __restrict__ Opart, const float* __restrict__ mlpart,
    bf16_t* __restrict__ attn) {
  int ti = 6 + blockIdx.x;
  int bh = blockIdx.y, b = bh >> 4, hh = bh & 15;
  int ns = ti / 6 + 1;
  int base_idx = (ti < 12) ? (ti - 6) * 2 : 12 + (ti - 12) * 3;
  int r = threadIdx.x >> 1;
  int dh = (threadIdx.x & 1) * 32;

  float w[3], den = 0.f;
  for (int s = 0; s < ns; ++s) {
    long slot = (long)bh * 24 + base_idx + s;
    w[s] = mlpart[slot * 256 + r];
    den += w[s];
  }
  float inv = 1.f / den;
  float acc[32];
#pragma unroll
  for (int d = 0; d < 32; ++d) acc[d] = 0.f;
  for (int s = 0; s < ns; ++s) {
    long slot = (long)bh * 24 + base_idx + s;
    const bf16_t* op = Opart + slot * (128 * 64) + r * 64 + dh;
#pragma unroll
    for (int d = 0; d < 32; ++d) acc[d] += w[s] * (float)op[d];
  }
  long rowg = (long)b * T_ + ti * 128 + r;
  bf16_t* dst = attn + rowg * E_ + hh * HS_ + dh;
#pragma unroll
  for (int d = 0; d < 32; ++d) dst[d] = (bf16_t)(acc[d] * inv);
}

// ---------------------------------------------------------------------------
extern "C" void kernel_launch(void* const* d_in, const int* in_sizes, int n_in,
                              void* d_out, int out_size, void* d_ws,
                              size_t ws_size, hipStream_t stream) {
  const float* x = (const float*)d_in[0];
  const float* ln1_g = (const float*)d_in[1];
  const float* ln1_b = (const float*)d_in[2];
  const float* Wq = (const float*)d_in[3];
  const float* bq = (const float*)d_in[4];
  const float* Wk = (const float*)d_in[5];
  const float* bk = (const float*)d_in[6];
  const float* Wv = (const float*)d_in[7];
  const float* bv = (const float*)d_in[8];
  const float* Wp = (const float*)d_in[9];
  const float* bp = (const float*)d_in[10];
  const float* ln2_g = (const float*)d_in[11];
  const float* ln2_b = (const float*)d_in[12];
  const float* W1 = (const float*)d_in[13];
  const float* b1 = (const float*)d_in[14];
  const float* W2 = (const float*)d_in[15];
  const float* b2 = (const float*)d_in[16];
  float* out = (float*)d_out;

  const size_t MB = 1ull << 20;
  char* ws = (char*)d_ws;
  bf16_t* wqkvt = (bf16_t*)(ws + 0 * MB);   // [3072][1024] bf16 = 6 MB
  bf16_t* wpt   = (bf16_t*)(ws + 6 * MB);   // 2 MB
  bf16_t* w1t   = (bf16_t*)(ws + 8 * MB);   // 8 MB
  bf16_t* w2t   = (bf16_t*)(ws + 16 * MB);  // 8 MB
  float*  bqkv  = (float*)(ws + 24 * MB);   // 12 KB
  bf16_t* h     = (bf16_t*)(ws + 25 * MB);  // [8192][1024] 16 MB; reused: attn, h2
  bf16_t* qkvb  = (bf16_t*)(ws + 41 * MB);  // [8192][3072] 48 MB; reused: ff1
  bf16_t* vt    = (bf16_t*)(ws + 89 * MB);  // [64][64][2048] 16 MB
  float*  xmid  = (float*)(ws + 105 * MB);  // 32 MB -> ends 137 MB
  // flash scratch overlaps xmid temporally (dead before proj writes xmid):
  bf16_t* Opart = (bf16_t*)(ws + 105 * MB); // 1536 slots * 8192 bf16 = 25.2 MB
  float* mlpart = (float*)(ws + 131 * MB);  // 1536 * 256 fp32 = 1.5 MB
  bf16_t* attn  = h;                        // h dead after QKV gemm
  bf16_t* h2    = h;                        // attn dead after proj gemm
  bf16_t* ff1   = qkvb;                     // qkv+vt dead after flash

  dim3 tb(32, 8);
  // weight transposes into fused QKV layout [3072][1024]
  wtrans_kernel<<<dim3(E_ / 32, E_ / 32), tb, 0, stream>>>(Wq, wqkvt, E_, E_);
  wtrans_kernel<<<dim3(E_ / 32, E_ / 32), tb, 0, stream>>>(Wk, wqkvt + (long)E_ * E_, E_, E_);
  wtrans_kernel<<<dim3(E_ / 32, E_ / 32), tb, 0, stream>>>(Wv, wqkvt + 2l * E_ * E_, E_, E_);
  wtrans_kernel<<<dim3(E_ / 32, E_ / 32), tb, 0, stream>>>(Wp, wpt, E_, E_);
  wtrans_kernel<<<dim3(DFF_ / 32, E_ / 32), tb, 0, stream>>>(W1, w1t, E_, DFF_);
  wtrans_kernel<<<dim3(E_ / 32, DFF_ / 32), tb, 0, stream>>>(W2, w2t, DFF_, E_);
  bcat_kernel<<<12, 256, 0, stream>>>(bq, bk, bv, bqkv);

  // LN1
  layernorm_kernel<<<M_, 256, 0, stream>>>(x, ln1_g, ln1_b, h);

  // fused QKV gemm: [8192][3072], 256x128 tiles -> 768 blocks = 3/CU exact.
  // MODE 2: also mirrors V columns into vt (replaces vtrans kernel).
  gemm256x128_kernel<2><<<dim3(3 * E_ / 128, M_ / 256), 512, 0, stream>>>(
      h, wqkvt, bqkv, nullptr, qkvb, vt, 3 * E_, E_);

  // flash attention, paired q-tiles (15 blocks per bh) + merge
  flash_attn_kernel<<<dim3(15, B_ * H_), 512, 0, stream>>>(qkvb, vt, attn,
                                                           Opart, mlpart);
  flash_merge_kernel<<<dim3(10, B_ * H_), 256, 0, stream>>>(Opart, mlpart, attn);

  // proj + residual -> xmid (fp32), 256x128 tiles -> 256 blocks = 1/CU
  gemm256x128_kernel<1><<<dim3(E_ / 128, M_ / 256), 512, 0, stream>>>(
      attn, wpt, bp, x, xmid, nullptr, E_, E_);

  // LN2
  layernorm_kernel<<<M_, 256, 0, stream>>>(xmid, ln2_g, ln2_b, h2);

  // FFN: FF1 [8192][4096] on 256x256 path (relu, 512 blk = 2/CU exact);
  // FF2 [8192][1024] K=4096 on 256x128 path (+resid, fp32 out)
  gemm256_kernel<1><<<dim3(DFF_ / 256, M_ / 256), 512, 0, stream>>>(
      h2, w1t, b1, ff1, DFF_, E_);
  gemm256x128_kernel<1><<<dim3(E_ / 128, M_ / 256), 512, 0, stream>>>(
      ff1, w2t, b2, xmid, out, nullptr, E_, DFF_);
}

// Round 8
// 492.140 us; speedup vs baseline: 1.0736x; 1.0410x over previous
//
#include <hip/hip_runtime.h>
#include <hip/hip_bf16.h>

#define B_ 4
#define T_ 2048
#define E_ 1024
#define H_ 16
#define HS_ 64
#define DFF_ 4096
#define M_ (B_ * T_)   // 8192 tokens
#define LDQ_ (3 * E_)  // qkv fused row stride

typedef __bf16 bf16_t;
typedef __bf16 bf16x4 __attribute__((ext_vector_type(4)));
typedef __bf16 bf16x8 __attribute__((ext_vector_type(8)));
typedef float f32x4 __attribute__((ext_vector_type(4)));

#define AS1 __attribute__((address_space(1)))
#define AS3 __attribute__((address_space(3)))

__device__ __forceinline__ void gload_lds16(const void* g, void* l) {
  __builtin_amdgcn_global_load_lds((AS1 void*)(g), (AS3 void*)(l), 16, 0, 0);
}

// ---------------------------------------------------------------------------
// Weight convert+transpose: W fp32 [Krows][Ncols] -> Wt bf16 [Ncols][Krows]
// ---------------------------------------------------------------------------
__global__ __launch_bounds__(256) void wtrans_kernel(
    const float* __restrict__ W, bf16_t* __restrict__ Wt, int Krows, int Ncols) {
  __shared__ float tile[32][33];
  int tx = threadIdx.x, ty = threadIdx.y;  // (32,8)
  int n0 = blockIdx.x * 32, k0 = blockIdx.y * 32;
#pragma unroll
  for (int i = 0; i < 32; i += 8)
    tile[ty + i][tx] = W[(long)(k0 + ty + i) * Ncols + n0 + tx];
  __syncthreads();
#pragma unroll
  for (int i = 0; i < 32; i += 8)
    Wt[(long)(n0 + ty + i) * Krows + k0 + tx] = (bf16_t)tile[tx][ty + i];
}

// bias concat: [bq | bk | bv] -> 3072 floats
__global__ __launch_bounds__(256) void bcat_kernel(const float* a, const float* b,
                                                   const float* c, float* o) {
  int i = blockIdx.x * 256 + threadIdx.x;
  o[i] = i < 1024 ? a[i] : (i < 2048 ? b[i - 1024] : c[i - 2048]);
}

// ---------------------------------------------------------------------------
// LayerNorm: fp32 [M][1024] -> bf16 [M][1024]
// ---------------------------------------------------------------------------
__global__ __launch_bounds__(256) void layernorm_kernel(
    const float* __restrict__ in, const float* __restrict__ g,
    const float* __restrict__ b, bf16_t* __restrict__ out) {
  int row = blockIdx.x;
  int tid = threadIdx.x;
  const float4* inr = (const float4*)(in + (long)row * E_);
  float4 v = inr[tid];
  float s = v.x + v.y + v.z + v.w;
  float ss = v.x * v.x + v.y * v.y + v.z * v.z + v.w * v.w;
#pragma unroll
  for (int o = 32; o; o >>= 1) {
    s += __shfl_xor(s, o);
    ss += __shfl_xor(ss, o);
  }
  __shared__ float red[8];
  int wv = tid >> 6;
  if ((tid & 63) == 0) {
    red[wv] = s;
    red[4 + wv] = ss;
  }
  __syncthreads();
  s = red[0] + red[1] + red[2] + red[3];
  ss = red[4] + red[5] + red[6] + red[7];
  float mu = s * (1.f / E_);
  float var = ss * (1.f / E_) - mu * mu;
  float rs = rsqrtf(var + 1e-5f);
  int ci = tid * 4;
  float4 gv = *(const float4*)(g + ci);
  float4 bv = *(const float4*)(b + ci);
  long o0 = (long)row * E_ + ci;
  out[o0 + 0] = (bf16_t)((v.x - mu) * rs * gv.x + bv.x);
  out[o0 + 1] = (bf16_t)((v.y - mu) * rs * gv.y + bv.y);
  out[o0 + 2] = (bf16_t)((v.z - mu) * rs * gv.z + bv.z);
  out[o0 + 3] = (bf16_t)((v.w - mu) * rs * gv.w + bv.w);
}

// ---------------------------------------------------------------------------
// GEMM (256x256 path, FF1): BK=32, 8 waves (2Mx4N, per-wave 128x64),
// 4-deep ring of K-tiles in statically-named LDS slots (alias-analysis-proof:
// r2 lesson), counted vmcnt, loop unrolled x4. K % 128 == 0.
// RELU 0: bf16 + bias; RELU 1: bf16 relu(+bias).
// ---------------------------------------------------------------------------
template <int RELU>
__global__ __launch_bounds__(512, 2) void gemm256_kernel(
    const bf16_t* __restrict__ A, const bf16_t* __restrict__ Bt,
    const float* __restrict__ bias, bf16_t* __restrict__ out, int N, int K) {
  __shared__ bf16_t As0[256 * 32], As1[256 * 32], As2[256 * 32], As3[256 * 32];
  __shared__ bf16_t Bs0[256 * 32], Bs1[256 * 32], Bs2[256 * 32], Bs3[256 * 32];
  const int tid = threadIdx.x;
  const int wave = tid >> 6;  // 0..7
  const int lane = tid & 63;
  const int wr = wave >> 2;   // 0..1 : row half (128 rows)
  const int wc = wave & 3;    // 0..3 : col quarter (64 cols)
  const int quad = lane >> 4, l16 = lane & 15;

  const int gx = gridDim.x;
  const int id = blockIdx.y * gx + blockIdx.x;
  const int xcd = id & 7;
  const int k_ = id >> 3;
  const int bxr = k_ % gx;
  const int byr = (k_ / gx) * 8 + xcd;
  const long rowBase = (long)byr * 256;
  const long colBase = (long)bxr * 256;

  f32x4 acc[8][4] = {};  // [mh*4+fr][fc]

  const int ntiles = K >> 5;  // multiple of 4

  auto stageA = [&](bf16_t* dst, int t) {
    const int k0 = t << 5;
#pragma unroll
    for (int p = 0; p < 2; ++p) {
      int idx = p * 512 + tid;  // chunk id 0..1023
      int row = idx >> 2;       // 0..255
      int col = (idx & 3) * 8;  // 0,8,16,24
      gload_lds16(&A[(rowBase + row) * K + k0 + col],
                  dst + (p * 512 + wave * 64) * 8);
    }
  };
  auto stageB = [&](bf16_t* dst, int t) {
    const int k0 = t << 5;
#pragma unroll
    for (int p = 0; p < 2; ++p) {
      int idx = p * 512 + tid;
      int row = idx >> 2;
      int col = (idx & 3) * 8;
      gload_lds16(&Bt[(colBase + row) * K + k0 + col],
                  dst + (p * 512 + wave * 64) * 8);
    }
  };

  auto tileStep = [&](int t, const bf16_t* as, const bf16_t* bs, bf16_t* nA,
                      bf16_t* nB) {
    const bool pre = (t + 3 < ntiles);
    bf16x8 bfrag[4];
#pragma unroll
    for (int fc = 0; fc < 4; ++fc)
      bfrag[fc] = *(const bf16x8*)&bs[(wc * 64 + fc * 16 + l16) * 32 + quad * 8];

    // ---- phase 0: row-half mh=0 ----
    {
      bf16x8 afrag[4];
#pragma unroll
      for (int fr = 0; fr < 4; ++fr)
        afrag[fr] =
            *(const bf16x8*)&as[(wr * 128 + fr * 16 + l16) * 32 + quad * 8];
      if (pre) stageA(nA, t + 3);
      __builtin_amdgcn_s_setprio(1);
#pragma unroll
      for (int fr = 0; fr < 4; ++fr)
#pragma unroll
        for (int fc = 0; fc < 4; ++fc)
          acc[fr][fc] = __builtin_amdgcn_mfma_f32_16x16x32_bf16(
              afrag[fr], bfrag[fc], acc[fr][fc], 0, 0, 0);
      __builtin_amdgcn_s_setprio(0);
      __builtin_amdgcn_s_barrier();
    }
    // ---- phase 1: row-half mh=1 ----
    {
      bf16x8 afrag[4];
#pragma unroll
      for (int fr = 0; fr < 4; ++fr)
        afrag[fr] = *(const bf16x8*)&as[(wr * 128 + 64 + fr * 16 + l16) * 32 +
                                        quad * 8];
      if (pre) stageB(nB, t + 3);
      __builtin_amdgcn_s_setprio(1);
#pragma unroll
      for (int fr = 0; fr < 4; ++fr)
#pragma unroll
        for (int fc = 0; fc < 4; ++fc)
          acc[4 + fr][fc] = __builtin_amdgcn_mfma_f32_16x16x32_bf16(
              afrag[fr], bfrag[fc], acc[4 + fr][fc], 0, 0, 0);
      __builtin_amdgcn_s_setprio(0);
      if (t + 3 < ntiles)
        asm volatile("s_waitcnt vmcnt(8)" ::: "memory");
      else if (t + 2 < ntiles)
        asm volatile("s_waitcnt vmcnt(4)" ::: "memory");
      else if (t + 1 < ntiles)
        asm volatile("s_waitcnt vmcnt(0)" ::: "memory");
      if (t + 1 < ntiles) __builtin_amdgcn_s_barrier();
    }
  };

  stageA(As0, 0); stageB(Bs0, 0);
  stageA(As1, 1); stageB(Bs1, 1);
  stageA(As2, 2); stageB(Bs2, 2);
  asm volatile("s_waitcnt vmcnt(8)" ::: "memory");
  __builtin_amdgcn_s_barrier();

  for (int t = 0; t < ntiles; t += 4) {
    tileStep(t + 0, As0, Bs0, As3, Bs3);
    tileStep(t + 1, As1, Bs1, As0, Bs0);
    tileStep(t + 2, As2, Bs2, As1, Bs1);
    tileStep(t + 3, As3, Bs3, As2, Bs2);
  }

#pragma unroll
  for (int mh = 0; mh < 2; ++mh)
#pragma unroll
    for (int fr = 0; fr < 4; ++fr)
#pragma unroll
      for (int fc = 0; fc < 4; ++fc) {
        int colg = (int)colBase + wc * 64 + fc * 16 + l16;
        float bv = bias[colg];
#pragma unroll
        for (int r = 0; r < 4; ++r) {
          long rowg = rowBase + wr * 128 + mh * 64 + fr * 16 + quad * 4 + r;
          float v = acc[mh * 4 + fr][fc][r] + bv;
          if (RELU) v = fmaxf(v, 0.f);
          out[rowg * N + colg] = (bf16_t)v;
        }
      }
}

// ---------------------------------------------------------------------------
// GEMM (256x128 path, QKV/proj/FF2): 8 waves (4r x 2c, per-wave 64x64).
// r8: 3-deep named ring (72KB LDS) -> __launch_bounds__(512,2) = 2 blocks/CU
// (was 4-deep/96KB/1 block -> occupancy-pinned at 17%, MfmaUtil 21%,
// VALUBusy 13%, nothing saturated = latency-bound; doubling resident blocks
// is the direct fix). Rotate-3: compute slot t%3, prefetch t+2 into
// (t+2)%3 (the slot consumed one barrier ago -- hazard-free), steady-state
// vmcnt(3) (tile t+1 landed, t+2's 3 loads in flight -> each tile gets 2
// iterations of flight time). 3 loads per K-tile (A:2, B:1). K % 32 == 0.
// MODE 0: bf16 C+bias; MODE 1: fp32 C+bias+resid. (r7's MODE 2 vt-fusion
// REVERTED: the vt scatter store was 4KB-strided across lanes -> partial-
// line write-allocate, FETCH 105MB, +30us. vtrans kernel restored.)
// ---------------------------------------------------------------------------
template <int MODE>
__global__ __launch_bounds__(512, 2) void gemm256x128_kernel(
    const bf16_t* __restrict__ A, const bf16_t* __restrict__ Bt,
    const float* __restrict__ bias, const float* __restrict__ resid,
    void* __restrict__ out, int N, int K) {
  __shared__ bf16_t As0[256 * 32], As1[256 * 32], As2[256 * 32];
  __shared__ bf16_t Bs0[128 * 32], Bs1[128 * 32], Bs2[128 * 32];
  const int tid = threadIdx.x;
  const int wave = tid >> 6;  // 0..7
  const int lane = tid & 63;
  const int wr = wave >> 1;   // 0..3 : 64-row band
  const int wc = wave & 1;    // 0..1 : 64-col half
  const int quad = lane >> 4, l16 = lane & 15;

  const int gx = gridDim.x;
  const int id = blockIdx.y * gx + blockIdx.x;
  const int xcd = id & 7;
  const int k_ = id >> 3;
  const int bxr = k_ % gx;
  const int byr = (k_ / gx) * 8 + xcd;
  const long rowBase = (long)byr * 256;
  const long colBase = (long)bxr * 128;

  f32x4 acc[4][4] = {};  // [fr][fc]

  const int ntiles = K >> 5;  // >= 4 for all our shapes

  auto stageA = [&](bf16_t* dst, int t) {
    const int k0 = t << 5;
#pragma unroll
    for (int p = 0; p < 2; ++p) {
      int idx = p * 512 + tid;
      int row = idx >> 2;       // 0..255
      int col = (idx & 3) * 8;  // 0,8,16,24
      gload_lds16(&A[(rowBase + row) * K + k0 + col],
                  dst + (p * 512 + wave * 64) * 8);
    }
  };
  auto stageB = [&](bf16_t* dst, int t) {
    const int k0 = t << 5;
    int row = tid >> 2;       // 0..127
    int col = (tid & 3) * 8;  // 0,8,16,24
    gload_lds16(&Bt[(colBase + row) * K + k0 + col], dst + (wave * 64) * 8);
  };

  auto tileStep = [&](int t, const bf16_t* as, const bf16_t* bs, bf16_t* nA,
                      bf16_t* nB) {
    const bool pre = (t + 2 < ntiles);
    bf16x8 bfrag[4];
#pragma unroll
    for (int fc = 0; fc < 4; ++fc)
      bfrag[fc] = *(const bf16x8*)&bs[(wc * 64 + fc * 16 + l16) * 32 + quad * 8];

    // ---- phase 0: rows fr=0,1 ----
    {
      bf16x8 afrag[2];
#pragma unroll
      for (int fr = 0; fr < 2; ++fr)
        afrag[fr] =
            *(const bf16x8*)&as[(wr * 64 + fr * 16 + l16) * 32 + quad * 8];
      if (pre) stageA(nA, t + 2);
      __builtin_amdgcn_s_setprio(1);
#pragma unroll
      for (int fr = 0; fr < 2; ++fr)
#pragma unroll
        for (int fc = 0; fc < 4; ++fc)
          acc[fr][fc] = __builtin_amdgcn_mfma_f32_16x16x32_bf16(
              afrag[fr], bfrag[fc], acc[fr][fc], 0, 0, 0);
      __builtin_amdgcn_s_setprio(0);
      __builtin_amdgcn_s_barrier();
    }
    // ---- phase 1: rows fr=2,3 ----
    {
      bf16x8 afrag[2];
#pragma unroll
      for (int fr = 2; fr < 4; ++fr)
        afrag[fr - 2] =
            *(const bf16x8*)&as[(wr * 64 + fr * 16 + l16) * 32 + quad * 8];
      if (pre) stageB(nB, t + 2);
      __builtin_amdgcn_s_setprio(1);
#pragma unroll
      for (int fr = 2; fr < 4; ++fr)
#pragma unroll
        for (int fc = 0; fc < 4; ++fc)
          acc[fr][fc] = __builtin_amdgcn_mfma_f32_16x16x32_bf16(
              afrag[fr - 2], bfrag[fc], acc[fr][fc], 0, 0, 0);
      __builtin_amdgcn_s_setprio(0);
      // in-flight after MFMAs: t+1's 3 loads (issued iter t-1, 3 left after
      // last wait) + t+2's 3 (issued this iter). Need t+1 landed -> vmcnt(3).
      if (t + 2 < ntiles)
        asm volatile("s_waitcnt vmcnt(3)" ::: "memory");
      else if (t + 1 < ntiles)
        asm volatile("s_waitcnt vmcnt(0)" ::: "memory");
      if (t + 1 < ntiles) __builtin_amdgcn_s_barrier();
    }
  };

  // prologue: stage tiles 0,1; wait tile 0 landed (tile 1's 3 may fly)
  stageA(As0, 0); stageB(Bs0, 0);
  stageA(As1, 1); stageB(Bs1, 1);
  asm volatile("s_waitcnt vmcnt(3)" ::: "memory");
  __builtin_amdgcn_s_barrier();

  int t = 0;
  while (true) {
    tileStep(t, As0, Bs0, As2, Bs2); if (++t >= ntiles) break;
    tileStep(t, As1, Bs1, As0, Bs0); if (++t >= ntiles) break;
    tileStep(t, As2, Bs2, As1, Bs1); if (++t >= ntiles) break;
  }

#pragma unroll
  for (int fr = 0; fr < 4; ++fr)
#pragma unroll
    for (int fc = 0; fc < 4; ++fc) {
      int colg = (int)colBase + wc * 64 + fc * 16 + l16;
      float bv = bias[colg];
#pragma unroll
      for (int r = 0; r < 4; ++r) {
        long rowg = rowBase + wr * 64 + fr * 16 + quad * 4 + r;
        float v = acc[fr][fc][r] + bv;
        long idx = rowg * N + colg;
        if (MODE == 0) {
          ((bf16_t*)out)[idx] = (bf16_t)v;
        } else {
          ((float*)out)[idx] = v + resid[idx];
        }
      }
    }
}

// ---------------------------------------------------------------------------
// V transpose: qkv bf16 [B*T][3072] v-part -> vt bf16 [b*h][d=64][t=2048]
// (restored from r4 -- coalesced LDS-tile transpose; the r7 epilogue-fused
// scatter version regressed QKV by ~30us.)
// ---------------------------------------------------------------------------
__global__ __launch_bounds__(256) void vtrans_kernel(
    const bf16_t* __restrict__ qkv, bf16_t* __restrict__ vt) {
  __shared__ bf16_t tile[32][33];
  int tx = threadIdx.x, ty = threadIdx.y;  // (32,8)
  int t0 = blockIdx.x * 32;
  int d0 = (blockIdx.y & 1) * 32;
  int bh = blockIdx.y >> 1;
  int b = bh >> 4, hh = bh & 15;
#pragma unroll
  for (int i = 0; i < 32; i += 8)
    tile[ty + i][tx] =
        qkv[(long)(b * T_ + t0 + ty + i) * LDQ_ + 2 * E_ + hh * HS_ + d0 + tx];
  __syncthreads();
#pragma unroll
  for (int i = 0; i < 32; i += 8)
    vt[((long)bh * HS_ + d0 + ty + i) * T_ + t0 + tx] = tile[tx][ty + i];
}

// ---------------------------------------------------------------------------
// Causal flash attention, KV-split, no-max softmax. S^T form.
// r7: PAIRED Q-TILES -- 512 threads / 8 waves; waves 0-3 own q-tile 2pt,
// waves 4-7 own 2pt+1, SHARING one K/V staging (dbuf + __syncthreads,
// KVBLK=64). Doubles waves/block, halves barrier count per unit work and
// K/V HBM traffic. nsplit(2pt)==nsplit(2pt+1) for every pair; causal check
// idles lower-tile waves past their extent; every sub-tile computes >=1
// iter. Grid 15x64, reversed decode (long blocks first). LDS 48KB.
// ---------------------------------------------------------------------------
__global__ __launch_bounds__(512) void flash_attn_kernel(
    const bf16_t* __restrict__ qkv, const bf16_t* __restrict__ vt,
    bf16_t* __restrict__ attn, bf16_t* __restrict__ Opart,
    float* __restrict__ mlpart) {
  int gx = 14 - (int)blockIdx.x;  // reversed: longest pairs first
  int pt = 0, sp = 0;
  for (int p = 0; p < 8; ++p) {
    int ns = (2 * p + 1) / 6 + 1;
    if (gx < ns) { pt = p; sp = gx; break; }
    gx -= ns;
  }

  const int tid = threadIdx.x;
  const int wave = tid >> 6;       // 0..7
  const int half = wave >> 2;      // 0: ti=2pt, 1: ti=2pt+1
  const int wsub = wave & 3;       // 32-row band within the wave's q-tile
  const int lane = tid & 63;
  const int quad = lane >> 4, l16 = lane & 15;
  const int bh = blockIdx.y, b = bh >> 4, hh = bh & 15;

  const int ti = 2 * pt + half;        // this wave's 128-row q-tile
  const int nsplit = ti / 6 + 1;
  const int qw = ti * 128 + wsub * 32;
  const int jbeg = 12 * sp;
  const int jendU = min(12 * sp + 12, 4 * pt + 4);  // union extent (upper)

  __shared__ __align__(16) bf16_t Ks[2][64 * 64];  // [kv][d], chunk-swizzled
  __shared__ __align__(16) bf16_t Vs[2][64 * 64];  // [d][kv], chunk-swizzled
  __shared__ __align__(16) bf16_t Ps[8][16 * 64];  // per-wave P^T, swizzled

  const bf16_t* qb = qkv;
  const bf16_t* kb = qkv + E_;

  // Q fragments, pre-scaled by HS^-0.5 = 0.125 (power of 2: exact in bf16)
  bf16x8 aq[2][2];
#pragma unroll
  for (int s = 0; s < 2; ++s) {
    long base = (long)(b * T_ + qw + s * 16 + l16) * LDQ_ + hh * HS_ + quad * 8;
    aq[s][0] = *(const bf16x8*)&qb[base];
    aq[s][1] = *(const bf16x8*)&qb[base + 32];
#pragma unroll
    for (int e = 0; e < 8; ++e) {
      aq[s][0][e] = (bf16_t)((float)aq[s][0][e] * 0.125f);
      aq[s][1][e] = (bf16_t)((float)aq[s][1][e] * 0.125f);
    }
  }

  f32x4 o[2][4] = {};     // O^T accumulator: [s][nt]; row d=quad*4+r, col q=l16
  float lsum[2] = {};     // per-lane row sums (q = qs + l16)

  // async stage of one K tile [64][64] + V^T tile [64][64] into buffer buf.
  // 512 threads x (1 K-chunk + 1 V-chunk); LDS dest linear (wave-uniform
  // base + lane*16); chunk-XOR swizzle on the per-lane GLOBAL source.
  auto stage = [&](int buf, int j) {
    const int kv0 = j * 64;
    int row = tid >> 3;                      // 0..63
    int gcol = ((tid & 7) ^ (row & 7)) * 8;  // swizzled 16B chunk
    gload_lds16(&kb[(long)(b * T_ + kv0 + row) * LDQ_ + hh * HS_ + gcol],
                &Ks[buf][wave * 512]);
    gload_lds16(&vt[((long)bh * HS_ + row) * T_ + kv0 + gcol],
                &Vs[buf][wave * 512]);
  };

  stage(0, jbeg);
  __syncthreads();

  for (int j = jbeg; j < jendU; ++j) {
    const int kv0 = j * 64;
    const int cur = (j - jbeg) & 1;
    if (j + 1 < jendU) stage(cur ^ 1, j + 1);  // prefetch next KV tile
    const bf16_t* KsL = Ks[cur];
    const bf16_t* VsL = Vs[cur];
    bf16_t* Pw = Ps[wave];

#pragma unroll
    for (int s = 0; s < 2; ++s) {
      const int qs = qw + s * 16;
      if (kv0 <= qs + 15) {
        // ---- S^T = K * Q^T : rows kv (quad*4+r per sub), col q (l16) ----
        f32x4 sc[4];
        __builtin_amdgcn_s_setprio(1);
#pragma unroll
        for (int sub = 0; sub < 4; ++sub) {
          const int rk = sub * 16 + l16;
          const int k0 = rk * 64 + ((quad ^ (rk & 7)) * 8);
          f32x4 t = {};
          t = __builtin_amdgcn_mfma_f32_16x16x32_bf16(
              *(const bf16x8*)&KsL[k0], aq[s][0], t, 0, 0, 0);
          t = __builtin_amdgcn_mfma_f32_16x16x32_bf16(
              *(const bf16x8*)&KsL[k0 ^ 32], aq[s][1], t, 0, 0, 0);
          sc[sub] = t;
        }
        __builtin_amdgcn_s_setprio(0);
        // ---- causal mask (diagonal tiles only): kv > q -> -inf ----
        if (kv0 + 63 > qs) {
          int qcol = qs + l16;
#pragma unroll
          for (int sub = 0; sub < 4; ++sub)
#pragma unroll
            for (int r = 0; r < 4; ++r) {
              int kvrow = kv0 + sub * 16 + quad * 4 + r;
              if (kvrow > qcol) sc[sub][r] = -INFINITY;
            }
        }
        // ---- p = exp(s); l accumulates per-lane ----
        float part = 0.f;
#pragma unroll
        for (int sub = 0; sub < 4; ++sub) {
#pragma unroll
          for (int r = 0; r < 4; ++r) sc[sub][r] = __expf(sc[sub][r]);
          part += (sc[sub][0] + sc[sub][1]) + (sc[sub][2] + sc[sub][3]);
        }
        lsum[s] += part;
        // ---- P^T -> LDS (swizzled): 4 consecutive kv per lane -> b64 ----
#pragma unroll
        for (int sub = 0; sub < 4; ++sub) {
          bf16x4 pk;
#pragma unroll
          for (int r = 0; r < 4; ++r) pk[r] = (bf16_t)sc[sub][r];
          const int ch = sub * 2 + (quad >> 1);
          const int off = ((ch ^ (l16 & 7)) * 8) + ((quad & 1) * 4);
          *(bf16x4*)&Pw[l16 * 64 + off] = pk;
        }
        // ---- O^T += V^T * P^T (intra-wave, no barrier) ----
        const int p0 = l16 * 64 + ((quad ^ (l16 & 7)) * 8);
        bf16x8 ap0 = *(const bf16x8*)&Pw[p0];
        bf16x8 ap1 = *(const bf16x8*)&Pw[p0 ^ 32];
        __builtin_amdgcn_s_setprio(1);
#pragma unroll
        for (int nt = 0; nt < 4; ++nt) {
          const int rv = nt * 16 + l16;
          const int v0 = rv * 64 + ((quad ^ (rv & 7)) * 8);
          o[s][nt] = __builtin_amdgcn_mfma_f32_16x16x32_bf16(
              *(const bf16x8*)&VsL[v0], ap0, o[s][nt], 0, 0, 0);
          o[s][nt] = __builtin_amdgcn_mfma_f32_16x16x32_bf16(
              *(const bf16x8*)&VsL[v0 ^ 32], ap1, o[s][nt], 0, 0, 0);
        }
        __builtin_amdgcn_s_setprio(0);
      }
    }
    __syncthreads();
  }

  // ---- l reduction across the 4 quads sharing each q ----
  float lval[2];
#pragma unroll
  for (int s = 0; s < 2; ++s) {
    float v = lsum[s];
    v += __shfl_xor(v, 16);
    v += __shfl_xor(v, 32);
    lval[s] = v;
  }

  if (nsplit == 1) {
#pragma unroll
    for (int s = 0; s < 2; ++s) {
      float inv = 1.f / lval[s];
      long rowg = (long)b * T_ + qw + s * 16 + l16;
#pragma unroll
      for (int nt = 0; nt < 4; ++nt) {
        bf16x4 pk;
#pragma unroll
        for (int r = 0; r < 4; ++r) pk[r] = (bf16_t)(o[s][nt][r] * inv);
        *(bf16x4*)&attn[rowg * E_ + hh * HS_ + nt * 16 + quad * 4] = pk;
      }
    }
  } else {
    int idx = (ti < 12) ? (ti - 6) * 2 + sp : 12 + (ti - 12) * 3 + sp;
    long slot = (long)bh * 24 + idx;
    bf16_t* op = Opart + slot * (128 * 64);
    float* ml = mlpart + slot * 256;
#pragma unroll
    for (int s = 0; s < 2; ++s) {
      float inv = 1.f / lval[s];
      int rloc = wsub * 32 + s * 16 + l16;
#pragma unroll
      for (int nt = 0; nt < 4; ++nt) {
        bf16x4 pk;
#pragma unroll
        for (int r = 0; r < 4; ++r) pk[r] = (bf16_t)(o[s][nt][r] * inv);
        *(bf16x4*)&op[rloc * 64 + nt * 16 + quad * 4] = pk;
      }
      if (quad == 0) ml[rloc] = lval[s];
    }
  }
}

// ---------------------------------------------------------------------------
// Merge partials for multi-split q-tiles (ti = 6..15): O = sum(l_s*Ohat_s)/sum(l_s)
// grid: (10, 64bh), 256 threads: thread = row(128) * 2 + d-half(32).
// ---------------------------------------------------------------------------
__global__ __launch_bounds__(256) void flash_merge_kernel(
    const bf16_t* __restrict__ Opart, const float* __restrict__ mlpart,
    bf16_t* __restrict__ attn) {
  int ti = 6 + blockIdx.x;
  int bh = blockIdx.y, b = bh >> 4, hh = bh & 15;
  int ns = ti / 6 + 1;
  int base_idx = (ti < 12) ? (ti - 6) * 2 : 12 + (ti - 12) * 3;
  int r = threadIdx.x >> 1;
  int dh = (threadIdx.x & 1) * 32;

  float w[3], den = 0.f;
  for (int s = 0; s < ns; ++s) {
    long slot = (long)bh * 24 + base_idx + s;
    w[s] = mlpart[slot * 256 + r];
    den += w[s];
  }
  float inv = 1.f / den;
  float acc[32];
#pragma unroll
  for (int d = 0; d < 32; ++d) acc[d] = 0.f;
  for (int s = 0; s < ns; ++s) {
    long slot = (long)bh * 24 + base_idx + s;
    const bf16_t* op = Opart + slot * (128 * 64) + r * 64 + dh;
#pragma unroll
    for (int d = 0; d < 32; ++d) acc[d] += w[s] * (float)op[d];
  }
  long rowg = (long)b * T_ + ti * 128 + r;
  bf16_t* dst = attn + rowg * E_ + hh * HS_ + dh;
#pragma unroll
  for (int d = 0; d < 32; ++d) dst[d] = (bf16_t)(acc[d] * inv);
}

// ---------------------------------------------------------------------------
extern "C" void kernel_launch(void* const* d_in, const int* in_sizes, int n_in,
                              void* d_out, int out_size, void* d_ws,
                              size_t ws_size, hipStream_t stream) {
  const float* x = (const float*)d_in[0];
  const float* ln1_g = (const float*)d_in[1];
  const float* ln1_b = (const float*)d_in[2];
  const float* Wq = (const float*)d_in[3];
  const float* bq = (const float*)d_in[4];
  const float* Wk = (const float*)d_in[5];
  const float* bk = (const float*)d_in[6];
  const float* Wv = (const float*)d_in[7];
  const float* bv = (const float*)d_in[8];
  const float* Wp = (const float*)d_in[9];
  const float* bp = (const float*)d_in[10];
  const float* ln2_g = (const float*)d_in[11];
  const float* ln2_b = (const float*)d_in[12];
  const float* W1 = (const float*)d_in[13];
  const float* b1 = (const float*)d_in[14];
  const float* W2 = (const float*)d_in[15];
  const float* b2 = (const float*)d_in[16];
  float* out = (float*)d_out;

  const size_t MB = 1ull << 20;
  char* ws = (char*)d_ws;
  bf16_t* wqkvt = (bf16_t*)(ws + 0 * MB);   // [3072][1024] bf16 = 6 MB
  bf16_t* wpt   = (bf16_t*)(ws + 6 * MB);   // 2 MB
  bf16_t* w1t   = (bf16_t*)(ws + 8 * MB);   // 8 MB
  bf16_t* w2t   = (bf16_t*)(ws + 16 * MB);  // 8 MB
  float*  bqkv  = (float*)(ws + 24 * MB);   // 12 KB
  bf16_t* h     = (bf16_t*)(ws + 25 * MB);  // [8192][1024] 16 MB; reused: attn, h2
  bf16_t* qkvb  = (bf16_t*)(ws + 41 * MB);  // [8192][3072] 48 MB; reused: ff1
  bf16_t* vt    = (bf16_t*)(ws + 89 * MB);  // [64][64][2048] 16 MB
  float*  xmid  = (float*)(ws + 105 * MB);  // 32 MB -> ends 137 MB
  // flash scratch overlaps xmid temporally (dead before proj writes xmid):
  bf16_t* Opart = (bf16_t*)(ws + 105 * MB); // 1536 slots * 8192 bf16 = 25.2 MB
  float* mlpart = (float*)(ws + 131 * MB);  // 1536 * 256 fp32 = 1.5 MB
  bf16_t* attn  = h;                        // h dead after QKV gemm
  bf16_t* h2    = h;                        // attn dead after proj gemm
  bf16_t* ff1   = qkvb;                     // qkv+vt dead after flash

  dim3 tb(32, 8);
  // weight transposes into fused QKV layout [3072][1024]
  wtrans_kernel<<<dim3(E_ / 32, E_ / 32), tb, 0, stream>>>(Wq, wqkvt, E_, E_);
  wtrans_kernel<<<dim3(E_ / 32, E_ / 32), tb, 0, stream>>>(Wk, wqkvt + (long)E_ * E_, E_, E_);
  wtrans_kernel<<<dim3(E_ / 32, E_ / 32), tb, 0, stream>>>(Wv, wqkvt + 2l * E_ * E_, E_, E_);
  wtrans_kernel<<<dim3(E_ / 32, E_ / 32), tb, 0, stream>>>(Wp, wpt, E_, E_);
  wtrans_kernel<<<dim3(DFF_ / 32, E_ / 32), tb, 0, stream>>>(W1, w1t, E_, DFF_);
  wtrans_kernel<<<dim3(E_ / 32, DFF_ / 32), tb, 0, stream>>>(W2, w2t, DFF_, E_);
  bcat_kernel<<<12, 256, 0, stream>>>(bq, bk, bv, bqkv);

  // LN1
  layernorm_kernel<<<M_, 256, 0, stream>>>(x, ln1_g, ln1_b, h);

  // fused QKV gemm: [8192][3072], 256x128 tiles -> 768 blocks, 2/CU resident
  gemm256x128_kernel<0><<<dim3(3 * E_ / 128, M_ / 256), 512, 0, stream>>>(
      h, wqkvt, bqkv, nullptr, qkvb, 3 * E_, E_);

  // V transpose to [bh][d][t]
  vtrans_kernel<<<dim3(T_ / 32, 2 * B_ * H_), tb, 0, stream>>>(qkvb, vt);

  // flash attention, paired q-tiles (15 blocks per bh) + merge
  flash_attn_kernel<<<dim3(15, B_ * H_), 512, 0, stream>>>(qkvb, vt, attn,
                                                           Opart, mlpart);
  flash_merge_kernel<<<dim3(10, B_ * H_), 256, 0, stream>>>(Opart, mlpart, attn);

  // proj + residual -> xmid (fp32), 256x128 tiles -> 256 blocks
  gemm256x128_kernel<1><<<dim3(E_ / 128, M_ / 256), 512, 0, stream>>>(
      attn, wpt, bp, x, xmid, E_, E_);

  // LN2
  layernorm_kernel<<<M_, 256, 0, stream>>>(xmid, ln2_g, ln2_b, h2);

  // FFN: FF1 [8192][4096] on 256x256 path (relu);
  // FF2 [8192][1024] K=4096 on 256x128 path (+resid, fp32 out)
  gemm256_kernel<1><<<dim3(DFF_ / 256, M_ / 256), 512, 0, stream>>>(
      h2, w1t, b1, ff1, DFF_, E_);
  gemm256x128_kernel<1><<<dim3(E_ / 128, M_ / 256), 512, 0, stream>>>(
      ff1, w2t, b2, xmid, out, E_, DFF_);
}